// Round 1
// baseline (2918.280 us; speedup 1.0000x reference)
//
#include <hip/hip_runtime.h>
#include <math.h>

#define HW   4096
#define NCH  256
#define NB   4
#define WDIM 64

constexpr float TEMP  = (float)(0.0001 * 5.0);
constexpr float INV_T = 1.0f / TEMP;
constexpr float EPSN  = 2.220446049250313e-16f;

// ---------------- workspace layout (in floats) ----------------
constexpr size_t OFF_THETA = 0;
constexpr size_t OFF_PHI   = OFF_THETA + (size_t)NB*NCH*HW;   // 4194304
constexpr size_t OFF_YT    = OFF_PHI   + (size_t)NB*NCH*HW;   // 8388608
constexpr size_t OFF_YI    = OFF_YT    + (size_t)NB*HW*NCH;   // 12582912
constexpr size_t OFF_MEAN  = OFF_YI    + (size_t)NB*3*HW;
constexpr size_t OFF_NORM  = OFF_MEAN  + (size_t)2*NB*NCH;
constexpr size_t OFF_NSQP  = OFF_NORM  + (size_t)2*NB*HW;
constexpr size_t OFF_F     = OFF_NSQP  + (size_t)2*NB*8*HW;
constexpr size_t OFF_RMAX  = OFF_F     + (size_t)HW*HW;
constexpr size_t OFF_RSUM  = OFF_RMAX  + HW;   // stores 1/rowsum
constexpr size_t OFF_CMAX  = OFF_RSUM  + HW;
constexpr size_t OFF_CSUM  = OFF_CMAX  + HW;   // stores 1/colsum
constexpr size_t OFF_CPM   = OFF_CSUM  + HW;           // 8*HW
constexpr size_t OFF_CPS   = OFF_CPM   + (size_t)8*HW;
constexpr size_t OFF_COORD = OFF_CPS   + (size_t)8*HW; // NB*2*HW
constexpr size_t OFF_ATTN  = OFF_COORD + (size_t)NB*2*HW;   // NB*HW*3
constexpr size_t OFF_CYC   = OFF_ATTN  + (size_t)NB*HW*3;   // NB*3*HW
constexpr size_t OFF_CYCP  = OFF_CYC   + (size_t)NB*3*HW;   // 8*3*HW
constexpr size_t OFF_LOSSP = OFF_CYCP  + (size_t)8*3*HW;    // 1024

// ---------------- output layout (floats) ----------------
constexpr size_t OUT_Y    = 0;
constexpr size_t OUT_FLOW = (size_t)NB*NCH*HW;                  // 4194304
constexpr size_t OUT_IMG  = OUT_FLOW + (size_t)NB*2*256*256;    // +524288
constexpr size_t OUT_CYCO = OUT_IMG  + (size_t)NB*3*256*256;    // +786432
constexpr size_t OUT_LOSS = OUT_CYCO + (size_t)NB*3*256*256;

// per-(b,c) spatial mean for both tensors
__global__ void mean_kernel(const float* __restrict__ xf, const float* __restrict__ yf,
                            float* __restrict__ means) {
    const float* src = (blockIdx.y == 0 ? xf : yf) + (size_t)blockIdx.x * HW;
    float s = 0.f;
    for (int i = threadIdx.x; i < HW; i += 256) s += src[i];
    __shared__ float red[256];
    red[threadIdx.x] = s; __syncthreads();
    for (int st = 128; st > 0; st >>= 1) {
        if (threadIdx.x < st) red[threadIdx.x] += red[threadIdx.x + st];
        __syncthreads();
    }
    if (threadIdx.x == 0) means[blockIdx.y * (NB*NCH) + blockIdx.x] = red[0] * (1.0f / HW);
}

// partial sum over channel-chunks of (x - mean)^2, per (tensor,b,m)
__global__ void nsq_partial_kernel(const float* __restrict__ xf, const float* __restrict__ yf,
                                   const float* __restrict__ means, float* __restrict__ part) {
    int t = blockIdx.z >> 2, b = blockIdx.z & 3;
    int m = blockIdx.x * 256 + threadIdx.x;
    int c0 = blockIdx.y * 32;
    const float* src = (t == 0 ? xf : yf) + (size_t)b * NCH * HW;
    const float* mn = means + t * (NB*NCH) + b * NCH;
    float acc = 0.f;
    for (int c = c0; c < c0 + 32; ++c) {
        float v = src[(size_t)c * HW + m] - mn[c];
        acc += v * v;
    }
    part[(((size_t)t*NB + b) * 8 + blockIdx.y) * HW + m] = acc;
}

__global__ void nsq_combine_kernel(const float* __restrict__ part, float* __restrict__ norms) {
    int t = blockIdx.y >> 2, b = blockIdx.y & 3;
    int m = blockIdx.x * 256 + threadIdx.x;
    const float* p = part + ((size_t)t*NB + b) * 8 * HW + m;
    float s = 0.f;
    for (int k = 0; k < 8; ++k) s += p[(size_t)k * HW];
    norms[((size_t)t*NB + b) * HW + m] = sqrtf(s) + EPSN;
}

__global__ void center_write_kernel(const float* __restrict__ xf, const float* __restrict__ yf,
                                    const float* __restrict__ means, const float* __restrict__ norms,
                                    float* __restrict__ theta, float* __restrict__ phi) {
    int t = blockIdx.y;
    size_t idx = (size_t)blockIdx.x * 256 + threadIdx.x;
    int m  = (int)(idx & (HW - 1));
    int bc = (int)(idx >> 12);
    int b  = bc >> 8;
    const float* src = (t == 0) ? xf : yf;
    float v = (src[idx] - means[t*(NB*NCH) + bc]) / norms[((size_t)t*NB + b)*HW + m];
    (t == 0 ? theta : phi)[idx] = v;
}

// YT[b][n][c] = y_feats[b][c][n]
__global__ void transpose_kernel(const float* __restrict__ yf, float* __restrict__ YT) {
    __shared__ float tile[32][33];
    int b = blockIdx.z;
    int c0 = blockIdx.x * 32, n0 = blockIdx.y * 32;
    int tx = threadIdx.x & 31, ty = threadIdx.x >> 5;  // 32x8
    for (int i = ty; i < 32; i += 8)
        tile[i][tx] = yf[((size_t)b*NCH + c0 + i) * HW + n0 + tx];
    __syncthreads();
    for (int i = ty; i < 32; i += 8)
        YT[((size_t)b*HW + n0 + i) * NCH + c0 + tx] = tile[tx][i];
}

// 4x4 average pool: y_img [B,3,256,256] -> yi [B,3,64,64]
__global__ void avgpool_kernel(const float* __restrict__ yimg, float* __restrict__ yi) {
    size_t idx = (size_t)blockIdx.x * 256 + threadIdx.x;  // over B*3*HW
    int m  = (int)(idx & (HW - 1));
    int bc = (int)(idx >> 12);
    int h = m >> 6, w = m & 63;
    const float* p = yimg + (size_t)bc * 65536 + (size_t)(h*4) * 256 + w*4;
    float s = 0.f;
    #pragma unroll
    for (int dy = 0; dy < 4; ++dy) {
        #pragma unroll
        for (int dx = 0; dx < 4; ++dx) s += p[dy*256 + dx];
    }
    yi[idx] = s * (1.0f/16.0f);
}

// f = theta_b^T @ phi_b : [4096 x 4096], tile 128x128, 8x8 micro per thread
__global__ __launch_bounds__(256) void gemm_f_kernel(const float* __restrict__ theta,
                                                     const float* __restrict__ phi,
                                                     float* __restrict__ f, int b) {
    __shared__ float As[16][128];
    __shared__ float Bs[16][128];
    const float* A  = theta + (size_t)b * NCH * HW;  // [c][m]
    const float* Bp = phi   + (size_t)b * NCH * HW;  // [c][n]
    int m0 = blockIdx.y * 128, n0 = blockIdx.x * 128;
    int tx = threadIdx.x & 15, ty = threadIdx.x >> 4;
    float acc[8][8];
    #pragma unroll
    for (int i = 0; i < 8; ++i)
        #pragma unroll
        for (int j = 0; j < 8; ++j) acc[i][j] = 0.f;

    for (int k0 = 0; k0 < NCH; k0 += 16) {
        #pragma unroll
        for (int ii = 0; ii < 8; ++ii) {
            int idx = ii*256 + threadIdx.x;
            int kk = idx >> 7, mm = idx & 127;
            As[kk][mm] = A [(size_t)(k0+kk)*HW + m0 + mm];
            Bs[kk][mm] = Bp[(size_t)(k0+kk)*HW + n0 + mm];
        }
        __syncthreads();
        #pragma unroll
        for (int kk = 0; kk < 16; ++kk) {
            float4 a0 = *(const float4*)&As[kk][ty*4];
            float4 a1 = *(const float4*)&As[kk][64 + ty*4];
            float4 b0 = *(const float4*)&Bs[kk][tx*4];
            float4 b1 = *(const float4*)&Bs[kk][64 + tx*4];
            float av[8] = {a0.x,a0.y,a0.z,a0.w, a1.x,a1.y,a1.z,a1.w};
            float bv[8] = {b0.x,b0.y,b0.z,b0.w, b1.x,b1.y,b1.z,b1.w};
            #pragma unroll
            for (int i = 0; i < 8; ++i)
                #pragma unroll
                for (int j = 0; j < 8; ++j)
                    acc[i][j] = fmaf(av[i], bv[j], acc[i][j]);
        }
        __syncthreads();
    }
    #pragma unroll
    for (int i = 0; i < 8; ++i) {
        int m = m0 + ((i < 4) ? (ty*4 + i) : (64 + ty*4 + i - 4));
        #pragma unroll
        for (int h = 0; h < 2; ++h) {
            float4 v = make_float4(acc[i][h*4+0], acc[i][h*4+1], acc[i][h*4+2], acc[i][h*4+3]);
            *(float4*)&f[(size_t)m*HW + n0 + h*64 + tx*4] = v;
        }
    }
}

// per-row: max, 1/sum(exp), coords (x,y), attn (3 ch)  — one block per row, row in LDS
__global__ __launch_bounds__(256) void row_stats_kernel(const float* __restrict__ f,
        const float* __restrict__ yi, float* __restrict__ rmax, float* __restrict__ rsuminv,
        float* __restrict__ coords, float* __restrict__ attn, int b) {
    __shared__ float row[HW];
    __shared__ float red[256];
    __shared__ float red6[6][256];
    int m = blockIdx.x, tid = threadIdx.x;
    const float* fr = f + (size_t)m * HW;
    float lmax = -3.0e38f;
    for (int i = tid; i < HW; i += 256) { float v = fr[i]; row[i] = v; lmax = fmaxf(lmax, v); }
    red[tid] = lmax; __syncthreads();
    for (int st = 128; st > 0; st >>= 1) {
        if (tid < st) red[tid] = fmaxf(red[tid], red[tid+st]);
        __syncthreads();
    }
    float rm = red[0];
    const float* yib = yi + (size_t)b * 3 * HW;
    float s=0, cx=0, cy=0, a0=0, a1=0, a2=0;
    for (int i = tid; i < HW; i += 256) {
        float e = __expf((row[i] - rm) * INV_T);
        s  += e;
        cx += e * (float)(i & 63);
        cy += e * (float)(i >> 6);
        a0 += e * yib[i];
        a1 += e * yib[HW + i];
        a2 += e * yib[2*HW + i];
    }
    red6[0][tid]=s; red6[1][tid]=cx; red6[2][tid]=cy;
    red6[3][tid]=a0; red6[4][tid]=a1; red6[5][tid]=a2;
    __syncthreads();
    for (int st = 128; st > 0; st >>= 1) {
        if (tid < st)
            for (int c = 0; c < 6; ++c) red6[c][tid] += red6[c][tid+st];
        __syncthreads();
    }
    if (tid == 0) {
        float inv = 1.0f / red6[0][0];
        rmax[m] = rm; rsuminv[m] = inv;
        coords[((size_t)b*2 + 0)*HW + m] = red6[1][0] * inv;
        coords[((size_t)b*2 + 1)*HW + m] = red6[2][0] * inv;
        attn[((size_t)b*HW + m)*3 + 0] = red6[3][0] * inv;
        attn[((size_t)b*HW + m)*3 + 1] = red6[4][0] * inv;
        attn[((size_t)b*HW + m)*3 + 2] = red6[5][0] * inv;
    }
}

// column softmax partials (online max+sum) over row-chunks of 512
__global__ void col_partial_kernel(const float* __restrict__ f,
                                   float* __restrict__ pmax, float* __restrict__ psum) {
    int n  = blockIdx.x * 256 + threadIdx.x;
    int j0 = blockIdx.y * 512;
    float mx = -3.0e38f, s = 0.f;
    for (int j = j0; j < j0 + 512; ++j) {
        float v  = f[(size_t)j * HW + n];
        float nm = fmaxf(mx, v);
        s = s * __expf((mx - nm) * INV_T) + __expf((v - nm) * INV_T);
        mx = nm;
    }
    pmax[(size_t)blockIdx.y * HW + n] = mx;
    psum[(size_t)blockIdx.y * HW + n] = s;
}

__global__ void col_combine_kernel(const float* __restrict__ pmax, const float* __restrict__ psum,
                                   float* __restrict__ cmax, float* __restrict__ csuminv) {
    int n = blockIdx.x * 256 + threadIdx.x;
    float mx = -3.0e38f;
    for (int k = 0; k < 8; ++k) mx = fmaxf(mx, pmax[(size_t)k*HW + n]);
    float s = 0.f;
    for (int k = 0; k < 8; ++k)
        s += psum[(size_t)k*HW + n] * __expf((pmax[(size_t)k*HW + n] - mx) * INV_T);
    cmax[n] = mx;
    csuminv[n] = 1.0f / s;
}

// y = P @ y_feats^T, P recomputed from f during staging. tile 128m x 128c
__global__ __launch_bounds__(256) void gemm_y_kernel(const float* __restrict__ f,
        const float* __restrict__ rmax, const float* __restrict__ rsuminv,
        const float* __restrict__ YT, float* __restrict__ out, int b) {
    __shared__ float Ps[16][132];   // padded: stride 132 avoids 16-way write conflicts
    __shared__ float Bs[16][128];
    int m0 = blockIdx.y * 128, c0 = blockIdx.x * 128;
    int tid = threadIdx.x;
    int tx = tid & 15, ty = tid >> 4;
    const float* YTb = YT + (size_t)b * HW * NCH;

    int smm[8], skk[8];
    float rmv[8];
    #pragma unroll
    for (int ii = 0; ii < 8; ++ii) {
        int idx = ii*256 + tid;
        skk[ii] = idx & 15; smm[ii] = idx >> 4;
        rmv[ii] = rmax[m0 + smm[ii]];
    }
    float acc[8][8];
    #pragma unroll
    for (int i = 0; i < 8; ++i)
        #pragma unroll
        for (int j = 0; j < 8; ++j) acc[i][j] = 0.f;

    for (int k0 = 0; k0 < HW; k0 += 16) {
        #pragma unroll
        for (int ii = 0; ii < 8; ++ii) {
            float v = f[(size_t)(m0 + smm[ii])*HW + k0 + skk[ii]];
            Ps[skk[ii]][smm[ii]] = __expf((v - rmv[ii]) * INV_T);
            int idx = ii*256 + tid;
            int kk2 = idx >> 7, cc = idx & 127;
            Bs[kk2][cc] = YTb[(size_t)(k0 + kk2)*NCH + c0 + cc];
        }
        __syncthreads();
        #pragma unroll
        for (int kk = 0; kk < 16; ++kk) {
            float4 a0 = *(const float4*)&Ps[kk][tx*4];
            float4 a1 = *(const float4*)&Ps[kk][64 + tx*4];
            float4 b0 = *(const float4*)&Bs[kk][ty*4];
            float4 b1 = *(const float4*)&Bs[kk][64 + ty*4];
            float av[8] = {a0.x,a0.y,a0.z,a0.w, a1.x,a1.y,a1.z,a1.w};
            float bv[8] = {b0.x,b0.y,b0.z,b0.w, b1.x,b1.y,b1.z,b1.w};
            #pragma unroll
            for (int i = 0; i < 8; ++i)     // i: m
                #pragma unroll
                for (int j = 0; j < 8; ++j) // j: c
                    acc[i][j] = fmaf(av[i], bv[j], acc[i][j]);
        }
        __syncthreads();
    }
    float4 r0 = *(const float4*)&rsuminv[m0 + tx*4];
    float4 r1 = *(const float4*)&rsuminv[m0 + 64 + tx*4];
    float ri[8] = {r0.x,r0.y,r0.z,r0.w, r1.x,r1.y,r1.z,r1.w};
    #pragma unroll
    for (int j = 0; j < 8; ++j) {
        int c = c0 + ((j < 4) ? (ty*4 + j) : (64 + ty*4 + j - 4));
        float* dst = out + OUT_Y + ((size_t)b*NCH + c)*HW;
        float4 v0 = make_float4(acc[0][j]*ri[0], acc[1][j]*ri[1], acc[2][j]*ri[2], acc[3][j]*ri[3]);
        float4 v1 = make_float4(acc[4][j]*ri[4], acc[5][j]*ri[5], acc[6][j]*ri[6], acc[7][j]*ri[7]);
        *(float4*)&dst[m0 + tx*4]      = v0;
        *(float4*)&dst[m0 + 64 + tx*4] = v1;
    }
}

// cyc partial: sum_j exp((f[j,i]-cmax[i])/T) * attn[j,c]  over row-chunks of 512
__global__ __launch_bounds__(256) void cyc_partial_kernel(const float* __restrict__ f,
        const float* __restrict__ cmax, const float* __restrict__ attn,
        float* __restrict__ part, int b) {
    __shared__ float at[512*3];
    int i  = blockIdx.x * 256 + threadIdx.x;
    int j0 = blockIdx.y * 512;
    for (int k = threadIdx.x; k < 1536; k += 256)
        at[k] = attn[((size_t)b*HW + j0)*3 + k];
    __syncthreads();
    float cm = cmax[i];
    float a0=0, a1=0, a2=0;
    for (int jj = 0; jj < 512; ++jj) {
        float e = __expf((f[(size_t)(j0+jj)*HW + i] - cm) * INV_T);
        a0 = fmaf(e, at[jj*3+0], a0);
        a1 = fmaf(e, at[jj*3+1], a1);
        a2 = fmaf(e, at[jj*3+2], a2);
    }
    part[((size_t)blockIdx.y*3 + 0)*HW + i] = a0;
    part[((size_t)blockIdx.y*3 + 1)*HW + i] = a1;
    part[((size_t)blockIdx.y*3 + 2)*HW + i] = a2;
}

__global__ void cyc_combine_kernel(const float* __restrict__ part, const float* __restrict__ csuminv,
                                   float* __restrict__ cyc, int b) {
    int i = blockIdx.x * 256 + threadIdx.x;
    int c = blockIdx.y;
    float s = 0.f;
    for (int k = 0; k < 8; ++k) s += part[((size_t)k*3 + c)*HW + i];
    cyc[((size_t)b*3 + c)*HW + i] = s * csuminv[i];
}

// flow = up4(coords1 - grid)
__global__ void flow_kernel(const float* __restrict__ coords, float* __restrict__ out) {
    size_t idx = (size_t)blockIdx.x * 256 + threadIdx.x;  // [4][2][256][256]
    int x4 = (int)(idx & 255);
    int y4 = (int)((idx >> 8) & 255);
    int ch = (int)((idx >> 16) & 1);
    int b  = (int)(idx >> 17);
    int w = x4 >> 2, h = y4 >> 2;
    int m = h*64 + w;
    float c1 = coords[((size_t)b*2 + ch)*HW + m];
    float c0 = (ch == 0) ? (float)w : (float)h;
    out[OUT_FLOW + idx] = c1 - c0;
}

// up4 of y_img_out (from attn) and y_img_cyc
__global__ void imgout_kernel(const float* __restrict__ attn, const float* __restrict__ cyc,
                              float* __restrict__ out) {
    size_t idx = (size_t)blockIdx.x * 256 + threadIdx.x;  // [4][3][256][256]
    int x4 = (int)(idx & 255);
    int y4 = (int)((idx >> 8) & 255);
    int rest = (int)(idx >> 16);    // b*3 + ch
    int ch = rest % 3, b = rest / 3;
    int m = (y4 >> 2)*64 + (x4 >> 2);
    out[OUT_IMG  + idx] = attn[((size_t)b*HW + m)*3 + ch];
    out[OUT_CYCO + idx] = cyc[((size_t)b*3 + ch)*HW + m];
}

__global__ void loss_partial_kernel(const float* __restrict__ theta, const float* __restrict__ phi,
                                    float* __restrict__ part) {
    __shared__ float red[256];
    size_t base = (size_t)blockIdx.x * 4096;
    float s = 0.f;
    for (int k = 0; k < 16; ++k) {
        size_t id = base + (size_t)k*256 + threadIdx.x;
        s += fabsf(theta[id] - phi[id]);
    }
    red[threadIdx.x] = s; __syncthreads();
    for (int st = 128; st > 0; st >>= 1) {
        if (threadIdx.x < st) red[threadIdx.x] += red[threadIdx.x + st];
        __syncthreads();
    }
    if (threadIdx.x == 0) part[blockIdx.x] = red[0];
}

__global__ void loss_final_kernel(const float* __restrict__ part, float* __restrict__ out) {
    __shared__ float red[256];
    float s = 0.f;
    for (int k = threadIdx.x; k < 1024; k += 256) s += part[k];
    red[threadIdx.x] = s; __syncthreads();
    for (int st = 128; st > 0; st >>= 1) {
        if (threadIdx.x < st) red[threadIdx.x] += red[threadIdx.x + st];
        __syncthreads();
    }
    if (threadIdx.x == 0) out[OUT_LOSS] = red[0] * (1.0f / 4194304.0f);
}

extern "C" void kernel_launch(void* const* d_in, const int* in_sizes, int n_in,
                              void* d_out, int out_size, void* d_ws, size_t ws_size,
                              hipStream_t stream) {
    (void)in_sizes; (void)n_in; (void)out_size; (void)ws_size;
    const float* xf   = (const float*)d_in[0];
    const float* yf   = (const float*)d_in[1];
    const float* yimg = (const float*)d_in[2];
    float* out = (float*)d_out;
    float* ws  = (float*)d_ws;

    float* theta   = ws + OFF_THETA;
    float* phi     = ws + OFF_PHI;
    float* YT      = ws + OFF_YT;
    float* yi      = ws + OFF_YI;
    float* means   = ws + OFF_MEAN;
    float* norms   = ws + OFF_NORM;
    float* nsqp    = ws + OFF_NSQP;
    float* fbuf    = ws + OFF_F;
    float* rmax    = ws + OFF_RMAX;
    float* rsuminv = ws + OFF_RSUM;
    float* cmax    = ws + OFF_CMAX;
    float* csuminv = ws + OFF_CSUM;
    float* cpm     = ws + OFF_CPM;
    float* cps     = ws + OFF_CPS;
    float* coords  = ws + OFF_COORD;
    float* attn    = ws + OFF_ATTN;
    float* cyc     = ws + OFF_CYC;
    float* cycp    = ws + OFF_CYCP;
    float* lossp   = ws + OFF_LOSSP;

    mean_kernel        <<<dim3(NB*NCH, 2),   256, 0, stream>>>(xf, yf, means);
    nsq_partial_kernel <<<dim3(16, 8, 8),    256, 0, stream>>>(xf, yf, means, nsqp);
    nsq_combine_kernel <<<dim3(16, 8),       256, 0, stream>>>(nsqp, norms);
    center_write_kernel<<<dim3(16384, 2),    256, 0, stream>>>(xf, yf, means, norms, theta, phi);
    transpose_kernel   <<<dim3(8, 128, NB),  256, 0, stream>>>(yf, YT);
    avgpool_kernel     <<<NB*3*HW/256,       256, 0, stream>>>(yimg, yi);

    for (int b = 0; b < NB; ++b) {
        gemm_f_kernel      <<<dim3(32, 32), 256, 0, stream>>>(theta, phi, fbuf, b);
        row_stats_kernel   <<<HW,           256, 0, stream>>>(fbuf, yi, rmax, rsuminv, coords, attn, b);
        col_partial_kernel <<<dim3(16, 8),  256, 0, stream>>>(fbuf, cpm, cps);
        col_combine_kernel <<<16,           256, 0, stream>>>(cpm, cps, cmax, csuminv);
        gemm_y_kernel      <<<dim3(2, 32),  256, 0, stream>>>(fbuf, rmax, rsuminv, YT, out, b);
        cyc_partial_kernel <<<dim3(16, 8),  256, 0, stream>>>(fbuf, cmax, attn, cycp, b);
        cyc_combine_kernel <<<dim3(16, 3),  256, 0, stream>>>(cycp, csuminv, cyc, b);
    }

    flow_kernel        <<<NB*2*65536/256, 256, 0, stream>>>(coords, out);
    imgout_kernel      <<<NB*3*65536/256, 256, 0, stream>>>(attn, cyc, out);
    loss_partial_kernel<<<1024,           256, 0, stream>>>(theta, phi, lossp);
    loss_final_kernel  <<<1,              256, 0, stream>>>(lossp, out);
}

// Round 2
// 1398.375 us; speedup vs baseline: 2.0869x; 2.0869x over previous
//
#include <hip/hip_runtime.h>
#include <math.h>

#define HW   4096
#define NCH  256
#define NB   4

constexpr float TEMP  = (float)(0.0001 * 5.0);
constexpr float INV_T = 1.0f / TEMP;
constexpr float EPSN  = 2.220446049250313e-16f;

// ---------------- workspace layout (in floats) ----------------
constexpr size_t OFF_YT    = 0;                                 // NB*HW*NCH
constexpr size_t OFF_YI    = OFF_YT    + (size_t)NB*HW*NCH;     // NB*3*HW
constexpr size_t OFF_MEAN  = OFF_YI    + (size_t)NB*3*HW;       // 2*NB*NCH
constexpr size_t OFF_RNORM = OFF_MEAN  + (size_t)2*NB*NCH;      // 2*NB*HW (stores 1/(||.||+eps))
constexpr size_t OFF_NSQP  = OFF_RNORM + (size_t)2*NB*HW;       // 2*NB*8*HW
constexpr size_t OFF_F     = OFF_NSQP  + (size_t)2*NB*8*HW;     // HW*HW
constexpr size_t OFF_YP    = OFF_F     + (size_t)HW*HW;         // 8*NCH*HW (split-K partials)
constexpr size_t OFF_RMAX  = OFF_YP    + (size_t)8*NCH*HW;
constexpr size_t OFF_RSUM  = OFF_RMAX  + HW;   // 1/rowsum
constexpr size_t OFF_CMAX  = OFF_RSUM  + HW;
constexpr size_t OFF_CSUM  = OFF_CMAX  + HW;   // 1/colsum
constexpr size_t OFF_CPM   = OFF_CSUM  + HW;            // 8*HW
constexpr size_t OFF_CPS   = OFF_CPM   + (size_t)8*HW;  // 8*HW
constexpr size_t OFF_COORD = OFF_CPS   + (size_t)8*HW;  // NB*2*HW
constexpr size_t OFF_ATTN  = OFF_COORD + (size_t)NB*2*HW;   // NB*HW*3
constexpr size_t OFF_CYC   = OFF_ATTN  + (size_t)NB*HW*3;   // NB*3*HW
constexpr size_t OFF_CYCP  = OFF_CYC   + (size_t)NB*3*HW;   // 8*3*HW
constexpr size_t OFF_LOSSP = OFF_CYCP  + (size_t)8*3*HW;    // 1024

// ---------------- output layout (floats) ----------------
constexpr size_t OUT_Y    = 0;
constexpr size_t OUT_FLOW = (size_t)NB*NCH*HW;
constexpr size_t OUT_IMG  = OUT_FLOW + (size_t)NB*2*256*256;
constexpr size_t OUT_CYCO = OUT_IMG  + (size_t)NB*3*256*256;
constexpr size_t OUT_LOSS = OUT_CYCO + (size_t)NB*3*256*256;

// per-(b,c) spatial mean for both tensors
__global__ void mean_kernel(const float* __restrict__ xf, const float* __restrict__ yf,
                            float* __restrict__ means) {
    const float* src = (blockIdx.y == 0 ? xf : yf) + (size_t)blockIdx.x * HW;
    float s = 0.f;
    for (int i = threadIdx.x; i < HW; i += 256) s += src[i];
    __shared__ float red[256];
    red[threadIdx.x] = s; __syncthreads();
    for (int st = 128; st > 0; st >>= 1) {
        if (threadIdx.x < st) red[threadIdx.x] += red[threadIdx.x + st];
        __syncthreads();
    }
    if (threadIdx.x == 0) means[blockIdx.y * (NB*NCH) + blockIdx.x] = red[0] * (1.0f / HW);
}

// partial sum over channel-chunks of (x - mean)^2, per (tensor,b,m)
__global__ void nsq_partial_kernel(const float* __restrict__ xf, const float* __restrict__ yf,
                                   const float* __restrict__ means, float* __restrict__ part) {
    int t = blockIdx.z >> 2, b = blockIdx.z & 3;
    int m = blockIdx.x * 256 + threadIdx.x;
    int c0 = blockIdx.y * 32;
    const float* src = (t == 0 ? xf : yf) + (size_t)b * NCH * HW;
    const float* mn = means + t * (NB*NCH) + b * NCH;
    float acc = 0.f;
    for (int c = c0; c < c0 + 32; ++c) {
        float v = src[(size_t)c * HW + m] - mn[c];
        acc += v * v;
    }
    part[(((size_t)t*NB + b) * 8 + blockIdx.y) * HW + m] = acc;
}

// stores RECIPROCAL of (||.|| + eps)
__global__ void nsq_combine_kernel(const float* __restrict__ part, float* __restrict__ rnorms) {
    int t = blockIdx.y >> 2, b = blockIdx.y & 3;
    int m = blockIdx.x * 256 + threadIdx.x;
    const float* p = part + ((size_t)t*NB + b) * 8 * HW + m;
    float s = 0.f;
    for (int k = 0; k < 8; ++k) s += p[(size_t)k * HW];
    rnorms[((size_t)t*NB + b) * HW + m] = 1.0f / (sqrtf(s) + EPSN);
}

// YT[b][n][c] = y_feats[b][c][n]
__global__ void transpose_kernel(const float* __restrict__ yf, float* __restrict__ YT) {
    __shared__ float tile[32][33];
    int b = blockIdx.z;
    int c0 = blockIdx.x * 32, n0 = blockIdx.y * 32;
    int tx = threadIdx.x & 31, ty = threadIdx.x >> 5;  // 32x8
    for (int i = ty; i < 32; i += 8)
        tile[i][tx] = yf[((size_t)b*NCH + c0 + i) * HW + n0 + tx];
    __syncthreads();
    for (int i = ty; i < 32; i += 8)
        YT[((size_t)b*HW + n0 + i) * NCH + c0 + tx] = tile[tx][i];
}

// 4x4 average pool: y_img [B,3,256,256] -> yi [B,3,64,64]
__global__ void avgpool_kernel(const float* __restrict__ yimg, float* __restrict__ yi) {
    size_t idx = (size_t)blockIdx.x * 256 + threadIdx.x;
    int m  = (int)(idx & (HW - 1));
    int bc = (int)(idx >> 12);
    int h = m >> 6, w = m & 63;
    const float* p = yimg + (size_t)bc * 65536 + (size_t)(h*4) * 256 + w*4;
    float s = 0.f;
    #pragma unroll
    for (int dy = 0; dy < 4; ++dy) {
        #pragma unroll
        for (int dx = 0; dx < 4; ++dx) s += p[dy*256 + dx];
    }
    yi[idx] = s * (1.0f/16.0f);
}

// f = theta^T @ phi with centering+normalization folded in.
// Stage (x - mean_c); scale epilogue by rnx[m]*rny[n].
__global__ __launch_bounds__(256) void gemm_f_kernel(const float* __restrict__ xf,
        const float* __restrict__ yf, const float* __restrict__ means,
        const float* __restrict__ rnorms, float* __restrict__ f, int b) {
    __shared__ float As[16][128];
    __shared__ float Bs[16][128];
    const float* A  = xf + (size_t)b * NCH * HW;  // [c][m]
    const float* Bp = yf + (size_t)b * NCH * HW;  // [c][n]
    const float* mx = means + b * NCH;
    const float* my = means + NB*NCH + b * NCH;
    int m0 = blockIdx.y * 128, n0 = blockIdx.x * 128;
    int tx = threadIdx.x & 15, ty = threadIdx.x >> 4;
    float acc[8][8];
    #pragma unroll
    for (int i = 0; i < 8; ++i)
        #pragma unroll
        for (int j = 0; j < 8; ++j) acc[i][j] = 0.f;

    for (int k0 = 0; k0 < NCH; k0 += 16) {
        #pragma unroll
        for (int ii = 0; ii < 8; ++ii) {
            int idx = ii*256 + threadIdx.x;
            int kk = idx >> 7, mm = idx & 127;
            As[kk][mm] = A [(size_t)(k0+kk)*HW + m0 + mm] - mx[k0+kk];
            Bs[kk][mm] = Bp[(size_t)(k0+kk)*HW + n0 + mm] - my[k0+kk];
        }
        __syncthreads();
        #pragma unroll
        for (int kk = 0; kk < 16; ++kk) {
            float4 a0 = *(const float4*)&As[kk][ty*4];
            float4 a1 = *(const float4*)&As[kk][64 + ty*4];
            float4 b0 = *(const float4*)&Bs[kk][tx*4];
            float4 b1 = *(const float4*)&Bs[kk][64 + tx*4];
            float av[8] = {a0.x,a0.y,a0.z,a0.w, a1.x,a1.y,a1.z,a1.w};
            float bv[8] = {b0.x,b0.y,b0.z,b0.w, b1.x,b1.y,b1.z,b1.w};
            #pragma unroll
            for (int i = 0; i < 8; ++i)
                #pragma unroll
                for (int j = 0; j < 8; ++j)
                    acc[i][j] = fmaf(av[i], bv[j], acc[i][j]);
        }
        __syncthreads();
    }
    const float* rnx = rnorms + (size_t)b * HW;        // t=0
    const float* rny = rnorms + (size_t)(NB + b) * HW; // t=1
    float4 ry0 = *(const float4*)&rny[n0 + tx*4];
    float4 ry1 = *(const float4*)&rny[n0 + 64 + tx*4];
    float ryv[8] = {ry0.x,ry0.y,ry0.z,ry0.w, ry1.x,ry1.y,ry1.z,ry1.w};
    #pragma unroll
    for (int i = 0; i < 8; ++i) {
        int m = m0 + ((i < 4) ? (ty*4 + i) : (64 + ty*4 + i - 4));
        float rx = rnx[m];
        #pragma unroll
        for (int h = 0; h < 2; ++h) {
            float4 v = make_float4(acc[i][h*4+0]*rx*ryv[h*4+0], acc[i][h*4+1]*rx*ryv[h*4+1],
                                   acc[i][h*4+2]*rx*ryv[h*4+2], acc[i][h*4+3]*rx*ryv[h*4+3]);
            *(float4*)&f[(size_t)m*HW + n0 + h*64 + tx*4] = v;
        }
    }
}

// per-row: max, 1/sum(exp), coords (x,y), attn (3 ch) — one block per row, row in LDS
__global__ __launch_bounds__(256) void row_stats_kernel(const float* __restrict__ f,
        const float* __restrict__ yi, float* __restrict__ rmax, float* __restrict__ rsuminv,
        float* __restrict__ coords, float* __restrict__ attn, int b) {
    __shared__ float row[HW];
    __shared__ float red[256];
    __shared__ float red6[6][256];
    int m = blockIdx.x, tid = threadIdx.x;
    const float* fr = f + (size_t)m * HW;
    float lmax = -3.0e38f;
    for (int i = tid; i < HW; i += 256) { float v = fr[i]; row[i] = v; lmax = fmaxf(lmax, v); }
    red[tid] = lmax; __syncthreads();
    for (int st = 128; st > 0; st >>= 1) {
        if (tid < st) red[tid] = fmaxf(red[tid], red[tid+st]);
        __syncthreads();
    }
    float rm = red[0];
    const float* yib = yi + (size_t)b * 3 * HW;
    float s=0, cx=0, cy=0, a0=0, a1=0, a2=0;
    for (int i = tid; i < HW; i += 256) {
        float e = __expf((row[i] - rm) * INV_T);
        s  += e;
        cx += e * (float)(i & 63);
        cy += e * (float)(i >> 6);
        a0 += e * yib[i];
        a1 += e * yib[HW + i];
        a2 += e * yib[2*HW + i];
    }
    red6[0][tid]=s; red6[1][tid]=cx; red6[2][tid]=cy;
    red6[3][tid]=a0; red6[4][tid]=a1; red6[5][tid]=a2;
    __syncthreads();
    for (int st = 128; st > 0; st >>= 1) {
        if (tid < st)
            for (int c = 0; c < 6; ++c) red6[c][tid] += red6[c][tid+st];
        __syncthreads();
    }
    if (tid == 0) {
        float inv = 1.0f / red6[0][0];
        rmax[m] = rm; rsuminv[m] = inv;
        coords[((size_t)b*2 + 0)*HW + m] = red6[1][0] * inv;
        coords[((size_t)b*2 + 1)*HW + m] = red6[2][0] * inv;
        attn[((size_t)b*HW + m)*3 + 0] = red6[3][0] * inv;
        attn[((size_t)b*HW + m)*3 + 1] = red6[4][0] * inv;
        attn[((size_t)b*HW + m)*3 + 2] = red6[5][0] * inv;
    }
}

// column softmax partials (online max+sum) over row-chunks of 512
__global__ void col_partial_kernel(const float* __restrict__ f,
                                   float* __restrict__ pmax, float* __restrict__ psum) {
    int n  = blockIdx.x * 256 + threadIdx.x;
    int j0 = blockIdx.y * 512;
    float mx = -3.0e38f, s = 0.f;
    for (int j = j0; j < j0 + 512; ++j) {
        float v  = f[(size_t)j * HW + n];
        float nm = fmaxf(mx, v);
        s = s * __expf((mx - nm) * INV_T) + __expf((v - nm) * INV_T);
        mx = nm;
    }
    pmax[(size_t)blockIdx.y * HW + n] = mx;
    psum[(size_t)blockIdx.y * HW + n] = s;
}

__global__ void col_combine_kernel(const float* __restrict__ pmax, const float* __restrict__ psum,
                                   float* __restrict__ cmax, float* __restrict__ csuminv) {
    int n = blockIdx.x * 256 + threadIdx.x;
    float mx = -3.0e38f;
    for (int k = 0; k < 8; ++k) mx = fmaxf(mx, pmax[(size_t)k*HW + n]);
    float s = 0.f;
    for (int k = 0; k < 8; ++k)
        s += psum[(size_t)k*HW + n] * __expf((pmax[(size_t)k*HW + n] - mx) * INV_T);
    cmax[n] = mx;
    csuminv[n] = 1.0f / s;
}

// y partials = P(kslice) @ y_feats^T, P recomputed from f during staging.
// grid (c-tiles=2, m-tiles=32, ks=8); each block covers k in [ks*512, ks*512+512)
__global__ __launch_bounds__(256) void gemm_y_kernel(const float* __restrict__ f,
        const float* __restrict__ rmax, const float* __restrict__ YT,
        float* __restrict__ yp, int b) {
    __shared__ float Ps[16][132];
    __shared__ float Bs[16][128];
    int m0 = blockIdx.y * 128, c0 = blockIdx.x * 128;
    int ks = blockIdx.z;
    int tid = threadIdx.x;
    int tx = tid & 15, ty = tid >> 4;
    const float* YTb = YT + (size_t)b * HW * NCH;

    int smm[8], skk[8];
    float rmv[8];
    #pragma unroll
    for (int ii = 0; ii < 8; ++ii) {
        int idx = ii*256 + tid;
        skk[ii] = idx & 15; smm[ii] = idx >> 4;
        rmv[ii] = rmax[m0 + smm[ii]];
    }
    float acc[8][8];
    #pragma unroll
    for (int i = 0; i < 8; ++i)
        #pragma unroll
        for (int j = 0; j < 8; ++j) acc[i][j] = 0.f;

    for (int k0 = ks*512; k0 < ks*512 + 512; k0 += 16) {
        #pragma unroll
        for (int ii = 0; ii < 8; ++ii) {
            float v = f[(size_t)(m0 + smm[ii])*HW + k0 + skk[ii]];
            Ps[skk[ii]][smm[ii]] = __expf((v - rmv[ii]) * INV_T);
            int idx = ii*256 + tid;
            int kk2 = idx >> 7, cc = idx & 127;
            Bs[kk2][cc] = YTb[(size_t)(k0 + kk2)*NCH + c0 + cc];
        }
        __syncthreads();
        #pragma unroll
        for (int kk = 0; kk < 16; ++kk) {
            float4 a0 = *(const float4*)&Ps[kk][tx*4];
            float4 a1 = *(const float4*)&Ps[kk][64 + tx*4];
            float4 b0 = *(const float4*)&Bs[kk][ty*4];
            float4 b1 = *(const float4*)&Bs[kk][64 + ty*4];
            float av[8] = {a0.x,a0.y,a0.z,a0.w, a1.x,a1.y,a1.z,a1.w};
            float bv[8] = {b0.x,b0.y,b0.z,b0.w, b1.x,b1.y,b1.z,b1.w};
            #pragma unroll
            for (int i = 0; i < 8; ++i)     // i: m
                #pragma unroll
                for (int j = 0; j < 8; ++j) // j: c
                    acc[i][j] = fmaf(av[i], bv[j], acc[i][j]);
        }
        __syncthreads();
    }
    #pragma unroll
    for (int j = 0; j < 8; ++j) {
        int c = c0 + ((j < 4) ? (ty*4 + j) : (64 + ty*4 + j - 4));
        float* dst = yp + ((size_t)ks*NCH + c)*HW;
        float4 v0 = make_float4(acc[0][j], acc[1][j], acc[2][j], acc[3][j]);
        float4 v1 = make_float4(acc[4][j], acc[5][j], acc[6][j], acc[7][j]);
        *(float4*)&dst[m0 + tx*4]      = v0;
        *(float4*)&dst[m0 + 64 + tx*4] = v1;
    }
}

// fixed-order split-K combine (deterministic)
__global__ void ycombine_kernel(const float* __restrict__ yp, const float* __restrict__ rsuminv,
                                float* __restrict__ out, int b) {
    size_t idx = (size_t)blockIdx.x * 256 + threadIdx.x;  // over NCH*HW
    int m = (int)(idx & (HW - 1));
    float s = 0.f;
    #pragma unroll
    for (int k = 0; k < 8; ++k) s += yp[(size_t)k*NCH*HW + idx];
    out[OUT_Y + (size_t)b*NCH*HW + idx] = s * rsuminv[m];
}

// cyc partial: sum_j exp((f[j,i]-cmax[i])/T) * attn[j,c]  over row-chunks of 512
__global__ __launch_bounds__(256) void cyc_partial_kernel(const float* __restrict__ f,
        const float* __restrict__ cmax, const float* __restrict__ attn,
        float* __restrict__ part, int b) {
    __shared__ float at[512*3];
    int i  = blockIdx.x * 256 + threadIdx.x;
    int j0 = blockIdx.y * 512;
    for (int k = threadIdx.x; k < 1536; k += 256)
        at[k] = attn[((size_t)b*HW + j0)*3 + k];
    __syncthreads();
    float cm = cmax[i];
    float a0=0, a1=0, a2=0;
    for (int jj = 0; jj < 512; ++jj) {
        float e = __expf((f[(size_t)(j0+jj)*HW + i] - cm) * INV_T);
        a0 = fmaf(e, at[jj*3+0], a0);
        a1 = fmaf(e, at[jj*3+1], a1);
        a2 = fmaf(e, at[jj*3+2], a2);
    }
    part[((size_t)blockIdx.y*3 + 0)*HW + i] = a0;
    part[((size_t)blockIdx.y*3 + 1)*HW + i] = a1;
    part[((size_t)blockIdx.y*3 + 2)*HW + i] = a2;
}

__global__ void cyc_combine_kernel(const float* __restrict__ part, const float* __restrict__ csuminv,
                                   float* __restrict__ cyc, int b) {
    int i = blockIdx.x * 256 + threadIdx.x;
    int c = blockIdx.y;
    float s = 0.f;
    for (int k = 0; k < 8; ++k) s += part[((size_t)k*3 + c)*HW + i];
    cyc[((size_t)b*3 + c)*HW + i] = s * csuminv[i];
}

// flow = up4(coords1 - grid)
__global__ void flow_kernel(const float* __restrict__ coords, float* __restrict__ out) {
    size_t idx = (size_t)blockIdx.x * 256 + threadIdx.x;  // [4][2][256][256]
    int x4 = (int)(idx & 255);
    int y4 = (int)((idx >> 8) & 255);
    int ch = (int)((idx >> 16) & 1);
    int b  = (int)(idx >> 17);
    int w = x4 >> 2, h = y4 >> 2;
    int m = h*64 + w;
    float c1 = coords[((size_t)b*2 + ch)*HW + m];
    float c0 = (ch == 0) ? (float)w : (float)h;
    out[OUT_FLOW + idx] = c1 - c0;
}

// up4 of y_img_out (from attn) and y_img_cyc
__global__ void imgout_kernel(const float* __restrict__ attn, const float* __restrict__ cyc,
                              float* __restrict__ out) {
    size_t idx = (size_t)blockIdx.x * 256 + threadIdx.x;  // [4][3][256][256]
    int x4 = (int)(idx & 255);
    int y4 = (int)((idx >> 8) & 255);
    int rest = (int)(idx >> 16);    // b*3 + ch
    int ch = rest % 3, b = rest / 3;
    int m = (y4 >> 2)*64 + (x4 >> 2);
    out[OUT_IMG  + idx] = attn[((size_t)b*HW + m)*3 + ch];
    out[OUT_CYCO + idx] = cyc[((size_t)b*3 + ch)*HW + m];
}

// L1 loss computed on-the-fly from raw inputs (theta/phi never materialized)
__global__ void loss_partial_kernel(const float* __restrict__ xf, const float* __restrict__ yf,
                                    const float* __restrict__ means, const float* __restrict__ rnorms,
                                    float* __restrict__ part) {
    __shared__ float red[256];
    size_t base = (size_t)blockIdx.x * 4096;
    float s = 0.f;
    for (int k = 0; k < 16; ++k) {
        size_t id = base + (size_t)k*256 + threadIdx.x;
        int m  = (int)(id & (HW - 1));
        int bc = (int)(id >> 12);
        int b  = bc >> 8;
        float th = (xf[id] - means[bc])          * rnorms[(size_t)b*HW + m];
        float ph = (yf[id] - means[NB*NCH + bc]) * rnorms[(size_t)(NB + b)*HW + m];
        s += fabsf(th - ph);
    }
    red[threadIdx.x] = s; __syncthreads();
    for (int st = 128; st > 0; st >>= 1) {
        if (threadIdx.x < st) red[threadIdx.x] += red[threadIdx.x + st];
        __syncthreads();
    }
    if (threadIdx.x == 0) part[blockIdx.x] = red[0];
}

__global__ void loss_final_kernel(const float* __restrict__ part, float* __restrict__ out) {
    __shared__ float red[256];
    float s = 0.f;
    for (int k = threadIdx.x; k < 1024; k += 256) s += part[k];
    red[threadIdx.x] = s; __syncthreads();
    for (int st = 128; st > 0; st >>= 1) {
        if (threadIdx.x < st) red[threadIdx.x] += red[threadIdx.x + st];
        __syncthreads();
    }
    if (threadIdx.x == 0) out[OUT_LOSS] = red[0] * (1.0f / 4194304.0f);
}

extern "C" void kernel_launch(void* const* d_in, const int* in_sizes, int n_in,
                              void* d_out, int out_size, void* d_ws, size_t ws_size,
                              hipStream_t stream) {
    (void)in_sizes; (void)n_in; (void)out_size; (void)ws_size;
    const float* xf   = (const float*)d_in[0];
    const float* yf   = (const float*)d_in[1];
    const float* yimg = (const float*)d_in[2];
    float* out = (float*)d_out;
    float* ws  = (float*)d_ws;

    float* YT      = ws + OFF_YT;
    float* yi      = ws + OFF_YI;
    float* means   = ws + OFF_MEAN;
    float* rnorms  = ws + OFF_RNORM;
    float* nsqp    = ws + OFF_NSQP;
    float* fbuf    = ws + OFF_F;
    float* yp      = ws + OFF_YP;
    float* rmax    = ws + OFF_RMAX;
    float* rsuminv = ws + OFF_RSUM;
    float* cmax    = ws + OFF_CMAX;
    float* csuminv = ws + OFF_CSUM;
    float* cpm     = ws + OFF_CPM;
    float* cps     = ws + OFF_CPS;
    float* coords  = ws + OFF_COORD;
    float* attn    = ws + OFF_ATTN;
    float* cyc     = ws + OFF_CYC;
    float* cycp    = ws + OFF_CYCP;
    float* lossp   = ws + OFF_LOSSP;

    mean_kernel        <<<dim3(NB*NCH, 2),   256, 0, stream>>>(xf, yf, means);
    nsq_partial_kernel <<<dim3(16, 8, 8),    256, 0, stream>>>(xf, yf, means, nsqp);
    nsq_combine_kernel <<<dim3(16, 8),       256, 0, stream>>>(nsqp, rnorms);
    transpose_kernel   <<<dim3(8, 128, NB),  256, 0, stream>>>(yf, YT);
    avgpool_kernel     <<<NB*3*HW/256,       256, 0, stream>>>(yimg, yi);

    for (int b = 0; b < NB; ++b) {
        gemm_f_kernel      <<<dim3(32, 32),    256, 0, stream>>>(xf, yf, means, rnorms, fbuf, b);
        row_stats_kernel   <<<HW,              256, 0, stream>>>(fbuf, yi, rmax, rsuminv, coords, attn, b);
        col_partial_kernel <<<dim3(16, 8),     256, 0, stream>>>(fbuf, cpm, cps);
        col_combine_kernel <<<16,              256, 0, stream>>>(cpm, cps, cmax, csuminv);
        gemm_y_kernel      <<<dim3(2, 32, 8),  256, 0, stream>>>(fbuf, rmax, YT, yp, b);
        ycombine_kernel    <<<NCH*HW/256,      256, 0, stream>>>(yp, rsuminv, out, b);
        cyc_partial_kernel <<<dim3(16, 8),     256, 0, stream>>>(fbuf, cmax, attn, cycp, b);
        cyc_combine_kernel <<<dim3(16, 3),     256, 0, stream>>>(cycp, csuminv, cyc, b);
    }

    flow_kernel        <<<NB*2*65536/256, 256, 0, stream>>>(coords, out);
    imgout_kernel      <<<NB*3*65536/256, 256, 0, stream>>>(attn, cyc, out);
    loss_partial_kernel<<<1024,           256, 0, stream>>>(xf, yf, means, rnorms, lossp);
    loss_final_kernel  <<<1,              256, 0, stream>>>(lossp, out);
}

// Round 3
// 1138.436 us; speedup vs baseline: 2.5634x; 1.2283x over previous
//
#include <hip/hip_runtime.h>
#include <math.h>

#define HW   4096
#define NCH  256
#define NB   4

constexpr float TEMP  = (float)(0.0001 * 5.0);
constexpr float INV_T = 1.0f / TEMP;
constexpr float EPSN  = 2.220446049250313e-16f;

typedef __attribute__((ext_vector_type(8))) _Float16 f16x8;
typedef __attribute__((ext_vector_type(4))) float    f32x4;

// ---------------- workspace layout (in floats) ----------------
constexpr size_t OFF_YT    = 0;                                 // NB*HW*NCH
constexpr size_t OFF_YI    = OFF_YT    + (size_t)NB*HW*NCH;     // NB*3*HW
constexpr size_t OFF_MEAN  = OFF_YI    + (size_t)NB*3*HW;       // 2*NB*NCH
constexpr size_t OFF_RNORM = OFF_MEAN  + (size_t)2*NB*NCH;      // 2*NB*HW (1/(||.||+eps))
constexpr size_t OFF_NSQP  = OFF_RNORM + (size_t)2*NB*HW;       // 2*NB*8*HW
constexpr size_t OFF_F     = OFF_NSQP  + (size_t)2*NB*8*HW;     // HW*HW
constexpr size_t OFF_YP    = OFF_F     + (size_t)HW*HW;         // 8*NCH*HW
constexpr size_t OFF_RMAX  = OFF_YP    + (size_t)8*NCH*HW;
constexpr size_t OFF_RSUM  = OFF_RMAX  + HW;
constexpr size_t OFF_CMAX  = OFF_RSUM  + HW;
constexpr size_t OFF_CSUM  = OFF_CMAX  + HW;
constexpr size_t OFF_CPM   = OFF_CSUM  + HW;            // 8*HW
constexpr size_t OFF_CPS   = OFF_CPM   + (size_t)8*HW;  // 8*HW
constexpr size_t OFF_COORD = OFF_CPS   + (size_t)8*HW;  // NB*2*HW
constexpr size_t OFF_ATTN  = OFF_COORD + (size_t)NB*2*HW;   // NB*HW*3
constexpr size_t OFF_CYC   = OFF_ATTN  + (size_t)NB*HW*3;   // NB*3*HW
constexpr size_t OFF_CYCP  = OFF_CYC   + (size_t)NB*3*HW;   // 8*3*HW
constexpr size_t OFF_LOSSP = OFF_CYCP  + (size_t)8*3*HW;    // 1024
// per-batch f16 hi/lo split arrays, [HW][NCH] layout, each HW*NCH f16 = 524288 floats
constexpr size_t OFF_F16   = OFF_LOSSP + 1024;              // 4 * 524288 floats

// ---------------- output layout (floats) ----------------
constexpr size_t OUT_Y    = 0;
constexpr size_t OUT_FLOW = (size_t)NB*NCH*HW;
constexpr size_t OUT_IMG  = OUT_FLOW + (size_t)NB*2*256*256;
constexpr size_t OUT_CYCO = OUT_IMG  + (size_t)NB*3*256*256;
constexpr size_t OUT_LOSS = OUT_CYCO + (size_t)NB*3*256*256;

__device__ __forceinline__ void gload16(const void* g, void* l) {
    __builtin_amdgcn_global_load_lds(
        (const __attribute__((address_space(1))) unsigned int*)g,
        (__attribute__((address_space(3))) unsigned int*)l, 16, 0, 0);
}

// per-(b,c) spatial mean for both tensors
__global__ void mean_kernel(const float* __restrict__ xf, const float* __restrict__ yf,
                            float* __restrict__ means) {
    const float* src = (blockIdx.y == 0 ? xf : yf) + (size_t)blockIdx.x * HW;
    float s = 0.f;
    for (int i = threadIdx.x; i < HW; i += 256) s += src[i];
    __shared__ float red[256];
    red[threadIdx.x] = s; __syncthreads();
    for (int st = 128; st > 0; st >>= 1) {
        if (threadIdx.x < st) red[threadIdx.x] += red[threadIdx.x + st];
        __syncthreads();
    }
    if (threadIdx.x == 0) means[blockIdx.y * (NB*NCH) + blockIdx.x] = red[0] * (1.0f / HW);
}

__global__ void nsq_partial_kernel(const float* __restrict__ xf, const float* __restrict__ yf,
                                   const float* __restrict__ means, float* __restrict__ part) {
    int t = blockIdx.z >> 2, b = blockIdx.z & 3;
    int m = blockIdx.x * 256 + threadIdx.x;
    int c0 = blockIdx.y * 32;
    const float* src = (t == 0 ? xf : yf) + (size_t)b * NCH * HW;
    const float* mn = means + t * (NB*NCH) + b * NCH;
    float acc = 0.f;
    for (int c = c0; c < c0 + 32; ++c) {
        float v = src[(size_t)c * HW + m] - mn[c];
        acc += v * v;
    }
    part[(((size_t)t*NB + b) * 8 + blockIdx.y) * HW + m] = acc;
}

__global__ void nsq_combine_kernel(const float* __restrict__ part, float* __restrict__ rnorms) {
    int t = blockIdx.y >> 2, b = blockIdx.y & 3;
    int m = blockIdx.x * 256 + threadIdx.x;
    const float* p = part + ((size_t)t*NB + b) * 8 * HW + m;
    float s = 0.f;
    for (int k = 0; k < 8; ++k) s += p[(size_t)k * HW];
    rnorms[((size_t)t*NB + b) * HW + m] = 1.0f / (sqrtf(s) + EPSN);
}

// YT[b][n][c] = y_feats[b][c][n]  (fp32, for gemm_y)
__global__ void transpose_kernel(const float* __restrict__ yf, float* __restrict__ YT) {
    __shared__ float tile[32][33];
    int b = blockIdx.z;
    int c0 = blockIdx.x * 32, n0 = blockIdx.y * 32;
    int tx = threadIdx.x & 31, ty = threadIdx.x >> 5;
    for (int i = ty; i < 32; i += 8)
        tile[i][tx] = yf[((size_t)b*NCH + c0 + i) * HW + n0 + tx];
    __syncthreads();
    for (int i = ty; i < 32; i += 8)
        YT[((size_t)b*HW + n0 + i) * NCH + c0 + tx] = tile[tx][i];
}

// centered hi/lo f16 split in transposed [m][c] layout (per batch)
__global__ void prep_kernel(const float* __restrict__ xf, const float* __restrict__ yf,
                            const float* __restrict__ means,
                            _Float16* __restrict__ th, _Float16* __restrict__ tl,
                            _Float16* __restrict__ ph, _Float16* __restrict__ pl, int b) {
    __shared__ float tile[32][33];
    int t = blockIdx.z;
    int c0 = blockIdx.x * 32, m0 = blockIdx.y * 32;
    const float* src = (t == 0 ? xf : yf) + (size_t)b * NCH * HW;
    const float* mn  = means + t * (NB*NCH) + b * NCH;
    int tx = threadIdx.x & 31, ty = threadIdx.x >> 5;
    for (int i = ty; i < 32; i += 8)
        tile[i][tx] = src[(size_t)(c0 + i) * HW + m0 + tx] - mn[c0 + i];
    __syncthreads();
    _Float16* H = (t == 0 ? th : ph);
    _Float16* L = (t == 0 ? tl : pl);
    for (int i = ty; i < 32; i += 8) {
        float v = tile[tx][i];              // c = c0+tx, m = m0+i
        _Float16 h = (_Float16)v;
        _Float16 l = (_Float16)(v - (float)h);
        H[(size_t)(m0 + i)*NCH + c0 + tx] = h;
        L[(size_t)(m0 + i)*NCH + c0 + tx] = l;
    }
}

// 4x4 average pool
__global__ void avgpool_kernel(const float* __restrict__ yimg, float* __restrict__ yi) {
    size_t idx = (size_t)blockIdx.x * 256 + threadIdx.x;
    int m  = (int)(idx & (HW - 1));
    int bc = (int)(idx >> 12);
    int h = m >> 6, w = m & 63;
    const float* p = yimg + (size_t)bc * 65536 + (size_t)(h*4) * 256 + w*4;
    float s = 0.f;
    #pragma unroll
    for (int dy = 0; dy < 4; ++dy) {
        #pragma unroll
        for (int dx = 0; dx < 4; ++dx) s += p[dy*256 + dx];
    }
    yi[idx] = s * (1.0f/16.0f);
}

// f = (hi+lo)x(hi+lo) MFMA GEMM, 128x128 tile, BK=32, 4 waves, epilogue rnx*rny
__global__ __launch_bounds__(256) void gemm_f_kernel(
        const _Float16* __restrict__ th, const _Float16* __restrict__ tl,
        const _Float16* __restrict__ ph, const _Float16* __restrict__ pl,
        const float* __restrict__ rnorms, float* __restrict__ f, int b) {
    __shared__ char lds[4][8192];   // Ah, Al, Bh, Bl tiles: [128 rows][32 k] f16, 64B rows
    int tid  = threadIdx.x;
    int lane = tid & 63;
    int w = tid >> 6, wm = w >> 1, wn = w & 1;
    int m0 = blockIdx.y * 128, n0 = blockIdx.x * 128;

    // staging: thread covers LDS bytes [o,o+16) at o0 and o0+4096 of each tile.
    // LDS is linear; the k-slot swizzle (slot ^= (row>>1)&3) is applied to the
    // GLOBAL source address (both-sides rule), so ds_read uses the same XOR.
    int o0 = tid * 16, o1 = o0 + 4096;
    int r0 = o0 >> 6, s0 = (o0 >> 4) & 3, g0 = s0 ^ ((r0 >> 1) & 3);
    int r1 = o1 >> 6, s1 = (o1 >> 4) & 3, g1 = s1 ^ ((r1 >> 1) & 3);
    size_t ga0 = (size_t)(m0 + r0)*NCH + g0*8;
    size_t ga1 = (size_t)(m0 + r1)*NCH + g1*8;
    size_t gb0 = (size_t)(n0 + r0)*NCH + g0*8;
    size_t gb1 = (size_t)(n0 + r1)*NCH + g1*8;

    int fra = wm*64 + (lane & 15);   // A fragment row base (+ i*16)
    int frb = wn*64 + (lane & 15);   // B fragment row base (+ j*16)
    int ks  = lane >> 4;             // k-slot (8 f16 each)

    f32x4 acc[4][4];
    #pragma unroll
    for (int i = 0; i < 4; ++i)
        #pragma unroll
        for (int j = 0; j < 4; ++j) acc[i][j] = (f32x4){0.f, 0.f, 0.f, 0.f};

    for (int kt = 0; kt < 8; ++kt) {
        int k0 = kt * 32;
        gload16(th + ga0 + k0, &lds[0][o0]);
        gload16(th + ga1 + k0, &lds[0][o1]);
        gload16(tl + ga0 + k0, &lds[1][o0]);
        gload16(tl + ga1 + k0, &lds[1][o1]);
        gload16(ph + gb0 + k0, &lds[2][o0]);
        gload16(ph + gb1 + k0, &lds[2][o1]);
        gload16(pl + gb0 + k0, &lds[3][o0]);
        gload16(pl + gb1 + k0, &lds[3][o1]);
        __syncthreads();   // compiler drains vmcnt before s_barrier

        f16x8 ah[4], al[4], bh[4], bl[4];
        #pragma unroll
        for (int i = 0; i < 4; ++i) {
            int rowa = fra + i*16;
            int offa = rowa*64 + ((ks ^ ((rowa >> 1) & 3)) << 4);
            ah[i] = *(const f16x8*)&lds[0][offa];
            al[i] = *(const f16x8*)&lds[1][offa];
            int rowb = frb + i*16;
            int offb = rowb*64 + ((ks ^ ((rowb >> 1) & 3)) << 4);
            bh[i] = *(const f16x8*)&lds[2][offb];
            bl[i] = *(const f16x8*)&lds[3][offb];
        }
        #pragma unroll
        for (int i = 0; i < 4; ++i)
            #pragma unroll
            for (int j = 0; j < 4; ++j) {
                acc[i][j] = __builtin_amdgcn_mfma_f32_16x16x32_f16(ah[i], bh[j], acc[i][j], 0, 0, 0);
                acc[i][j] = __builtin_amdgcn_mfma_f32_16x16x32_f16(ah[i], bl[j], acc[i][j], 0, 0, 0);
                acc[i][j] = __builtin_amdgcn_mfma_f32_16x16x32_f16(al[i], bh[j], acc[i][j], 0, 0, 0);
            }
        __syncthreads();
    }

    const float* rnx = rnorms + (size_t)b * HW;
    const float* rny = rnorms + (size_t)(NB + b) * HW;
    int colb = n0 + wn*64 + (lane & 15);
    int rowb = m0 + wm*64 + (lane >> 4) * 4;
    #pragma unroll
    for (int j = 0; j < 4; ++j) {
        int col = colb + j*16;
        float ry = rny[col];
        #pragma unroll
        for (int i = 0; i < 4; ++i) {
            int row = rowb + i*16;
            #pragma unroll
            for (int r = 0; r < 4; ++r)
                f[(size_t)(row + r)*HW + col] = acc[i][j][r] * rnx[row + r] * ry;
        }
    }
}

// per-row: max, 1/sum(exp), coords, attn — one block per row
__global__ __launch_bounds__(256) void row_stats_kernel(const float* __restrict__ f,
        const float* __restrict__ yi, float* __restrict__ rmax, float* __restrict__ rsuminv,
        float* __restrict__ coords, float* __restrict__ attn, int b) {
    __shared__ float row[HW];
    __shared__ float red[256];
    __shared__ float red6[6][256];
    int m = blockIdx.x, tid = threadIdx.x;
    const float* fr = f + (size_t)m * HW;
    float lmax = -3.0e38f;
    for (int i = tid; i < HW; i += 256) { float v = fr[i]; row[i] = v; lmax = fmaxf(lmax, v); }
    red[tid] = lmax; __syncthreads();
    for (int st = 128; st > 0; st >>= 1) {
        if (tid < st) red[tid] = fmaxf(red[tid], red[tid+st]);
        __syncthreads();
    }
    float rm = red[0];
    const float* yib = yi + (size_t)b * 3 * HW;
    float s=0, cx=0, cy=0, a0=0, a1=0, a2=0;
    for (int i = tid; i < HW; i += 256) {
        float e = __expf((row[i] - rm) * INV_T);
        s  += e;
        cx += e * (float)(i & 63);
        cy += e * (float)(i >> 6);
        a0 += e * yib[i];
        a1 += e * yib[HW + i];
        a2 += e * yib[2*HW + i];
    }
    red6[0][tid]=s; red6[1][tid]=cx; red6[2][tid]=cy;
    red6[3][tid]=a0; red6[4][tid]=a1; red6[5][tid]=a2;
    __syncthreads();
    for (int st = 128; st > 0; st >>= 1) {
        if (tid < st)
            for (int c = 0; c < 6; ++c) red6[c][tid] += red6[c][tid+st];
        __syncthreads();
    }
    if (tid == 0) {
        float inv = 1.0f / red6[0][0];
        rmax[m] = rm; rsuminv[m] = inv;
        coords[((size_t)b*2 + 0)*HW + m] = red6[1][0] * inv;
        coords[((size_t)b*2 + 1)*HW + m] = red6[2][0] * inv;
        attn[((size_t)b*HW + m)*3 + 0] = red6[3][0] * inv;
        attn[((size_t)b*HW + m)*3 + 1] = red6[4][0] * inv;
        attn[((size_t)b*HW + m)*3 + 2] = red6[5][0] * inv;
    }
}

__global__ void col_partial_kernel(const float* __restrict__ f,
                                   float* __restrict__ pmax, float* __restrict__ psum) {
    int n  = blockIdx.x * 256 + threadIdx.x;
    int j0 = blockIdx.y * 512;
    float mx = -3.0e38f, s = 0.f;
    for (int j = j0; j < j0 + 512; ++j) {
        float v  = f[(size_t)j * HW + n];
        float nm = fmaxf(mx, v);
        s = s * __expf((mx - nm) * INV_T) + __expf((v - nm) * INV_T);
        mx = nm;
    }
    pmax[(size_t)blockIdx.y * HW + n] = mx;
    psum[(size_t)blockIdx.y * HW + n] = s;
}

__global__ void col_combine_kernel(const float* __restrict__ pmax, const float* __restrict__ psum,
                                   float* __restrict__ cmax, float* __restrict__ csuminv) {
    int n = blockIdx.x * 256 + threadIdx.x;
    float mx = -3.0e38f;
    for (int k = 0; k < 8; ++k) mx = fmaxf(mx, pmax[(size_t)k*HW + n]);
    float s = 0.f;
    for (int k = 0; k < 8; ++k)
        s += psum[(size_t)k*HW + n] * __expf((pmax[(size_t)k*HW + n] - mx) * INV_T);
    cmax[n] = mx;
    csuminv[n] = 1.0f / s;
}

// y partials = P(kslice) @ y_feats^T (split-K over 8 slices)
__global__ __launch_bounds__(256) void gemm_y_kernel(const float* __restrict__ f,
        const float* __restrict__ rmax, const float* __restrict__ YT,
        float* __restrict__ yp, int b) {
    __shared__ float Ps[16][132];
    __shared__ float Bs[16][128];
    int m0 = blockIdx.y * 128, c0 = blockIdx.x * 128;
    int ks = blockIdx.z;
    int tid = threadIdx.x;
    int tx = tid & 15, ty = tid >> 4;
    const float* YTb = YT + (size_t)b * HW * NCH;

    int smm[8], skk[8];
    float rmv[8];
    #pragma unroll
    for (int ii = 0; ii < 8; ++ii) {
        int idx = ii*256 + tid;
        skk[ii] = idx & 15; smm[ii] = idx >> 4;
        rmv[ii] = rmax[m0 + smm[ii]];
    }
    float acc[8][8];
    #pragma unroll
    for (int i = 0; i < 8; ++i)
        #pragma unroll
        for (int j = 0; j < 8; ++j) acc[i][j] = 0.f;

    for (int k0 = ks*512; k0 < ks*512 + 512; k0 += 16) {
        #pragma unroll
        for (int ii = 0; ii < 8; ++ii) {
            float v = f[(size_t)(m0 + smm[ii])*HW + k0 + skk[ii]];
            Ps[skk[ii]][smm[ii]] = __expf((v - rmv[ii]) * INV_T);
            int idx = ii*256 + tid;
            int kk2 = idx >> 7, cc = idx & 127;
            Bs[kk2][cc] = YTb[(size_t)(k0 + kk2)*NCH + c0 + cc];
        }
        __syncthreads();
        #pragma unroll
        for (int kk = 0; kk < 16; ++kk) {
            float4 a0 = *(const float4*)&Ps[kk][tx*4];
            float4 a1 = *(const float4*)&Ps[kk][64 + tx*4];
            float4 b0 = *(const float4*)&Bs[kk][ty*4];
            float4 b1 = *(const float4*)&Bs[kk][64 + ty*4];
            float av[8] = {a0.x,a0.y,a0.z,a0.w, a1.x,a1.y,a1.z,a1.w};
            float bv[8] = {b0.x,b0.y,b0.z,b0.w, b1.x,b1.y,b1.z,b1.w};
            #pragma unroll
            for (int i = 0; i < 8; ++i)
                #pragma unroll
                for (int j = 0; j < 8; ++j)
                    acc[i][j] = fmaf(av[i], bv[j], acc[i][j]);
        }
        __syncthreads();
    }
    #pragma unroll
    for (int j = 0; j < 8; ++j) {
        int c = c0 + ((j < 4) ? (ty*4 + j) : (64 + ty*4 + j - 4));
        float* dst = yp + ((size_t)ks*NCH + c)*HW;
        float4 v0 = make_float4(acc[0][j], acc[1][j], acc[2][j], acc[3][j]);
        float4 v1 = make_float4(acc[4][j], acc[5][j], acc[6][j], acc[7][j]);
        *(float4*)&dst[m0 + tx*4]      = v0;
        *(float4*)&dst[m0 + 64 + tx*4] = v1;
    }
}

__global__ void ycombine_kernel(const float* __restrict__ yp, const float* __restrict__ rsuminv,
                                float* __restrict__ out, int b) {
    size_t idx = (size_t)blockIdx.x * 256 + threadIdx.x;
    int m = (int)(idx & (HW - 1));
    float s = 0.f;
    #pragma unroll
    for (int k = 0; k < 8; ++k) s += yp[(size_t)k*NCH*HW + idx];
    out[OUT_Y + (size_t)b*NCH*HW + idx] = s * rsuminv[m];
}

__global__ __launch_bounds__(256) void cyc_partial_kernel(const float* __restrict__ f,
        const float* __restrict__ cmax, const float* __restrict__ attn,
        float* __restrict__ part, int b) {
    __shared__ float at[512*3];
    int i  = blockIdx.x * 256 + threadIdx.x;
    int j0 = blockIdx.y * 512;
    for (int k = threadIdx.x; k < 1536; k += 256)
        at[k] = attn[((size_t)b*HW + j0)*3 + k];
    __syncthreads();
    float cm = cmax[i];
    float a0=0, a1=0, a2=0;
    for (int jj = 0; jj < 512; ++jj) {
        float e = __expf((f[(size_t)(j0+jj)*HW + i] - cm) * INV_T);
        a0 = fmaf(e, at[jj*3+0], a0);
        a1 = fmaf(e, at[jj*3+1], a1);
        a2 = fmaf(e, at[jj*3+2], a2);
    }
    part[((size_t)blockIdx.y*3 + 0)*HW + i] = a0;
    part[((size_t)blockIdx.y*3 + 1)*HW + i] = a1;
    part[((size_t)blockIdx.y*3 + 2)*HW + i] = a2;
}

__global__ void cyc_combine_kernel(const float* __restrict__ part, const float* __restrict__ csuminv,
                                   float* __restrict__ cyc, int b) {
    int i = blockIdx.x * 256 + threadIdx.x;
    int c = blockIdx.y;
    float s = 0.f;
    for (int k = 0; k < 8; ++k) s += part[((size_t)k*3 + c)*HW + i];
    cyc[((size_t)b*3 + c)*HW + i] = s * csuminv[i];
}

__global__ void flow_kernel(const float* __restrict__ coords, float* __restrict__ out) {
    size_t idx = (size_t)blockIdx.x * 256 + threadIdx.x;
    int x4 = (int)(idx & 255);
    int y4 = (int)((idx >> 8) & 255);
    int ch = (int)((idx >> 16) & 1);
    int b  = (int)(idx >> 17);
    int w = x4 >> 2, h = y4 >> 2;
    int m = h*64 + w;
    float c1 = coords[((size_t)b*2 + ch)*HW + m];
    float c0 = (ch == 0) ? (float)w : (float)h;
    out[OUT_FLOW + idx] = c1 - c0;
}

__global__ void imgout_kernel(const float* __restrict__ attn, const float* __restrict__ cyc,
                              float* __restrict__ out) {
    size_t idx = (size_t)blockIdx.x * 256 + threadIdx.x;
    int x4 = (int)(idx & 255);
    int y4 = (int)((idx >> 8) & 255);
    int rest = (int)(idx >> 16);
    int ch = rest % 3, b = rest / 3;
    int m = (y4 >> 2)*64 + (x4 >> 2);
    out[OUT_IMG  + idx] = attn[((size_t)b*HW + m)*3 + ch];
    out[OUT_CYCO + idx] = cyc[((size_t)b*3 + ch)*HW + m];
}

__global__ void loss_partial_kernel(const float* __restrict__ xf, const float* __restrict__ yf,
                                    const float* __restrict__ means, const float* __restrict__ rnorms,
                                    float* __restrict__ part) {
    __shared__ float red[256];
    size_t base = (size_t)blockIdx.x * 4096;
    float s = 0.f;
    for (int k = 0; k < 16; ++k) {
        size_t id = base + (size_t)k*256 + threadIdx.x;
        int m  = (int)(id & (HW - 1));
        int bc = (int)(id >> 12);
        int b  = bc >> 8;
        float th = (xf[id] - means[bc])          * rnorms[(size_t)b*HW + m];
        float ph = (yf[id] - means[NB*NCH + bc]) * rnorms[(size_t)(NB + b)*HW + m];
        s += fabsf(th - ph);
    }
    red[threadIdx.x] = s; __syncthreads();
    for (int st = 128; st > 0; st >>= 1) {
        if (threadIdx.x < st) red[threadIdx.x] += red[threadIdx.x + st];
        __syncthreads();
    }
    if (threadIdx.x == 0) part[blockIdx.x] = red[0];
}

__global__ void loss_final_kernel(const float* __restrict__ part, float* __restrict__ out) {
    __shared__ float red[256];
    float s = 0.f;
    for (int k = threadIdx.x; k < 1024; k += 256) s += part[k];
    red[threadIdx.x] = s; __syncthreads();
    for (int st = 128; st > 0; st >>= 1) {
        if (threadIdx.x < st) red[threadIdx.x] += red[threadIdx.x + st];
        __syncthreads();
    }
    if (threadIdx.x == 0) out[OUT_LOSS] = red[0] * (1.0f / 4194304.0f);
}

extern "C" void kernel_launch(void* const* d_in, const int* in_sizes, int n_in,
                              void* d_out, int out_size, void* d_ws, size_t ws_size,
                              hipStream_t stream) {
    (void)in_sizes; (void)n_in; (void)out_size; (void)ws_size;
    const float* xf   = (const float*)d_in[0];
    const float* yf   = (const float*)d_in[1];
    const float* yimg = (const float*)d_in[2];
    float* out = (float*)d_out;
    float* ws  = (float*)d_ws;

    float* YT      = ws + OFF_YT;
    float* yi      = ws + OFF_YI;
    float* means   = ws + OFF_MEAN;
    float* rnorms  = ws + OFF_RNORM;
    float* nsqp    = ws + OFF_NSQP;
    float* fbuf    = ws + OFF_F;
    float* yp      = ws + OFF_YP;
    float* rmax    = ws + OFF_RMAX;
    float* rsuminv = ws + OFF_RSUM;
    float* cmax    = ws + OFF_CMAX;
    float* csuminv = ws + OFF_CSUM;
    float* cpm     = ws + OFF_CPM;
    float* cps     = ws + OFF_CPS;
    float* coords  = ws + OFF_COORD;
    float* attn    = ws + OFF_ATTN;
    float* cyc     = ws + OFF_CYC;
    float* cycp    = ws + OFF_CYCP;
    float* lossp   = ws + OFF_LOSSP;
    _Float16* th = (_Float16*)(ws + OFF_F16);
    _Float16* tl = th + (size_t)HW*NCH;
    _Float16* ph = tl + (size_t)HW*NCH;
    _Float16* pl = ph + (size_t)HW*NCH;

    mean_kernel        <<<dim3(NB*NCH, 2),   256, 0, stream>>>(xf, yf, means);
    nsq_partial_kernel <<<dim3(16, 8, 8),    256, 0, stream>>>(xf, yf, means, nsqp);
    nsq_combine_kernel <<<dim3(16, 8),       256, 0, stream>>>(nsqp, rnorms);
    transpose_kernel   <<<dim3(8, 128, NB),  256, 0, stream>>>(yf, YT);
    avgpool_kernel     <<<NB*3*HW/256,       256, 0, stream>>>(yimg, yi);

    for (int b = 0; b < NB; ++b) {
        prep_kernel        <<<dim3(8, 128, 2), 256, 0, stream>>>(xf, yf, means, th, tl, ph, pl, b);
        gemm_f_kernel      <<<dim3(32, 32),    256, 0, stream>>>(th, tl, ph, pl, rnorms, fbuf, b);
        row_stats_kernel   <<<HW,              256, 0, stream>>>(fbuf, yi, rmax, rsuminv, coords, attn, b);
        col_partial_kernel <<<dim3(16, 8),     256, 0, stream>>>(fbuf, cpm, cps);
        col_combine_kernel <<<16,              256, 0, stream>>>(cpm, cps, cmax, csuminv);
        gemm_y_kernel      <<<dim3(2, 32, 8),  256, 0, stream>>>(fbuf, rmax, YT, yp, b);
        ycombine_kernel    <<<NCH*HW/256,      256, 0, stream>>>(yp, rsuminv, out, b);
        cyc_partial_kernel <<<dim3(16, 8),     256, 0, stream>>>(fbuf, cmax, attn, cycp, b);
        cyc_combine_kernel <<<dim3(16, 3),     256, 0, stream>>>(cycp, csuminv, cyc, b);
    }

    flow_kernel        <<<NB*2*65536/256, 256, 0, stream>>>(coords, out);
    imgout_kernel      <<<NB*3*65536/256, 256, 0, stream>>>(attn, cyc, out);
    loss_partial_kernel<<<1024,           256, 0, stream>>>(xf, yf, means, rnorms, lossp);
    loss_final_kernel  <<<1,              256, 0, stream>>>(lossp, out);
}

// Round 4
// 774.397 us; speedup vs baseline: 3.7685x; 1.4701x over previous
//
#include <hip/hip_runtime.h>
#include <math.h>

#define HW   4096
#define NCH  256
#define NB   4

constexpr float TEMP  = (float)(0.0001 * 5.0);
constexpr float INV_T = 1.0f / TEMP;
constexpr float EPSN  = 2.220446049250313e-16f;

typedef __attribute__((ext_vector_type(8))) _Float16 f16x8;
typedef __attribute__((ext_vector_type(4))) float    f32x4;

// ---------------- workspace layout (in floats) ----------------
constexpr size_t OFF_YT    = 0;                                 // yf16: NB*HW*NCH f16 (reuses YT slot)
constexpr size_t OFF_YI    = OFF_YT    + (size_t)NB*HW*NCH;     // NB*3*HW
constexpr size_t OFF_MEAN  = OFF_YI    + (size_t)NB*3*HW;       // 2*NB*NCH
constexpr size_t OFF_RNORM = OFF_MEAN  + (size_t)2*NB*NCH;      // 2*NB*HW (1/(||.||+eps))
constexpr size_t OFF_NSQP  = OFF_RNORM + (size_t)2*NB*HW;       // 2*NB*8*HW
constexpr size_t OFF_F     = OFF_NSQP  + (size_t)2*NB*8*HW;     // HW*HW
constexpr size_t OFF_YP    = OFF_F     + (size_t)HW*HW;         // 8*NCH*HW
constexpr size_t OFF_RMAX  = OFF_YP    + (size_t)8*NCH*HW;
constexpr size_t OFF_RSUM  = OFF_RMAX  + HW;
constexpr size_t OFF_CMAX  = OFF_RSUM  + HW;
constexpr size_t OFF_CSUM  = OFF_CMAX  + HW;
constexpr size_t OFF_CPM   = OFF_CSUM  + HW;            // 8*HW
constexpr size_t OFF_CPS   = OFF_CPM   + (size_t)8*HW;  // 8*HW
constexpr size_t OFF_COORD = OFF_CPS   + (size_t)8*HW;  // NB*2*HW
constexpr size_t OFF_ATTN  = OFF_COORD + (size_t)NB*2*HW;   // NB*HW*3
constexpr size_t OFF_CYC   = OFF_ATTN  + (size_t)NB*HW*3;   // NB*3*HW
constexpr size_t OFF_CYCP  = OFF_CYC   + (size_t)NB*3*HW;   // 8*3*HW
constexpr size_t OFF_LOSSP = OFF_CYCP  + (size_t)8*3*HW;    // 1024
constexpr size_t OFF_F16   = OFF_LOSSP + 1024;              // 4 * 524288 floats (th/tl/ph/pl)

// ---------------- output layout (floats) ----------------
constexpr size_t OUT_Y    = 0;
constexpr size_t OUT_FLOW = (size_t)NB*NCH*HW;
constexpr size_t OUT_IMG  = OUT_FLOW + (size_t)NB*2*256*256;
constexpr size_t OUT_CYCO = OUT_IMG  + (size_t)NB*3*256*256;
constexpr size_t OUT_LOSS = OUT_CYCO + (size_t)NB*3*256*256;

__device__ __forceinline__ void gload16(const void* g, void* l) {
    __builtin_amdgcn_global_load_lds(
        (const __attribute__((address_space(1))) unsigned int*)g,
        (__attribute__((address_space(3))) unsigned int*)l, 16, 0, 0);
}

// per-(b,c) spatial mean for both tensors
__global__ void mean_kernel(const float* __restrict__ xf, const float* __restrict__ yf,
                            float* __restrict__ means) {
    const float* src = (blockIdx.y == 0 ? xf : yf) + (size_t)blockIdx.x * HW;
    float s = 0.f;
    for (int i = threadIdx.x; i < HW; i += 256) s += src[i];
    __shared__ float red[256];
    red[threadIdx.x] = s; __syncthreads();
    for (int st = 128; st > 0; st >>= 1) {
        if (threadIdx.x < st) red[threadIdx.x] += red[threadIdx.x + st];
        __syncthreads();
    }
    if (threadIdx.x == 0) means[blockIdx.y * (NB*NCH) + blockIdx.x] = red[0] * (1.0f / HW);
}

__global__ void nsq_partial_kernel(const float* __restrict__ xf, const float* __restrict__ yf,
                                   const float* __restrict__ means, float* __restrict__ part) {
    int t = blockIdx.z >> 2, b = blockIdx.z & 3;
    int m = blockIdx.x * 256 + threadIdx.x;
    int c0 = blockIdx.y * 32;
    const float* src = (t == 0 ? xf : yf) + (size_t)b * NCH * HW;
    const float* mn = means + t * (NB*NCH) + b * NCH;
    float acc = 0.f;
    for (int c = c0; c < c0 + 32; ++c) {
        float v = src[(size_t)c * HW + m] - mn[c];
        acc += v * v;
    }
    part[(((size_t)t*NB + b) * 8 + blockIdx.y) * HW + m] = acc;
}

__global__ void nsq_combine_kernel(const float* __restrict__ part, float* __restrict__ rnorms) {
    int t = blockIdx.y >> 2, b = blockIdx.y & 3;
    int m = blockIdx.x * 256 + threadIdx.x;
    const float* p = part + ((size_t)t*NB + b) * 8 * HW + m;
    float s = 0.f;
    for (int k = 0; k < 8; ++k) s += p[(size_t)k * HW];
    rnorms[((size_t)t*NB + b) * HW + m] = 1.0f / (sqrtf(s) + EPSN);
}

// y_feats -> f16 (all batches), layout unchanged [b][c][n]
__global__ void ycast_kernel(const float* __restrict__ yf, _Float16* __restrict__ yf16) {
    size_t i = ((size_t)blockIdx.x * 256 + threadIdx.x) * 8;
    const float4* s = (const float4*)(yf + i);
    float4 v0 = s[0], v1 = s[1];
    f16x8 o;
    o[0]=(_Float16)v0.x; o[1]=(_Float16)v0.y; o[2]=(_Float16)v0.z; o[3]=(_Float16)v0.w;
    o[4]=(_Float16)v1.x; o[5]=(_Float16)v1.y; o[6]=(_Float16)v1.z; o[7]=(_Float16)v1.w;
    *(f16x8*)(yf16 + i) = o;
}

// centered hi/lo f16 split in transposed [m][c] layout (per batch)
__global__ void prep_kernel(const float* __restrict__ xf, const float* __restrict__ yf,
                            const float* __restrict__ means,
                            _Float16* __restrict__ th, _Float16* __restrict__ tl,
                            _Float16* __restrict__ ph, _Float16* __restrict__ pl, int b) {
    __shared__ float tile[32][33];
    int t = blockIdx.z;
    int c0 = blockIdx.x * 32, m0 = blockIdx.y * 32;
    const float* src = (t == 0 ? xf : yf) + (size_t)b * NCH * HW;
    const float* mn  = means + t * (NB*NCH) + b * NCH;
    int tx = threadIdx.x & 31, ty = threadIdx.x >> 5;
    for (int i = ty; i < 32; i += 8)
        tile[i][tx] = src[(size_t)(c0 + i) * HW + m0 + tx] - mn[c0 + i];
    __syncthreads();
    _Float16* H = (t == 0 ? th : ph);
    _Float16* L = (t == 0 ? tl : pl);
    for (int i = ty; i < 32; i += 8) {
        float v = tile[tx][i];
        _Float16 h = (_Float16)v;
        _Float16 l = (_Float16)(v - (float)h);
        H[(size_t)(m0 + i)*NCH + c0 + tx] = h;
        L[(size_t)(m0 + i)*NCH + c0 + tx] = l;
    }
}

// 4x4 average pool
__global__ void avgpool_kernel(const float* __restrict__ yimg, float* __restrict__ yi) {
    size_t idx = (size_t)blockIdx.x * 256 + threadIdx.x;
    int m  = (int)(idx & (HW - 1));
    int bc = (int)(idx >> 12);
    int h = m >> 6, w = m & 63;
    const float* p = yimg + (size_t)bc * 65536 + (size_t)(h*4) * 256 + w*4;
    float s = 0.f;
    #pragma unroll
    for (int dy = 0; dy < 4; ++dy) {
        #pragma unroll
        for (int dx = 0; dx < 4; ++dx) s += p[dy*256 + dx];
    }
    yi[idx] = s * (1.0f/16.0f);
}

// f = (hi+lo)x(hi+lo) MFMA GEMM, 128x128 tile, BK=32, 4 waves, epilogue rnx*rny
__global__ __launch_bounds__(256) void gemm_f_kernel(
        const _Float16* __restrict__ th, const _Float16* __restrict__ tl,
        const _Float16* __restrict__ ph, const _Float16* __restrict__ pl,
        const float* __restrict__ rnorms, float* __restrict__ f, int b) {
    __shared__ char lds[4][8192];
    int tid  = threadIdx.x;
    int lane = tid & 63;
    int w = tid >> 6, wm = w >> 1, wn = w & 1;
    int m0 = blockIdx.y * 128, n0 = blockIdx.x * 128;

    int o0 = tid * 16, o1 = o0 + 4096;
    int r0 = o0 >> 6, s0 = (o0 >> 4) & 3, g0 = s0 ^ ((r0 >> 1) & 3);
    int r1 = o1 >> 6, s1 = (o1 >> 4) & 3, g1 = s1 ^ ((r1 >> 1) & 3);
    size_t ga0 = (size_t)(m0 + r0)*NCH + g0*8;
    size_t ga1 = (size_t)(m0 + r1)*NCH + g1*8;
    size_t gb0 = (size_t)(n0 + r0)*NCH + g0*8;
    size_t gb1 = (size_t)(n0 + r1)*NCH + g1*8;

    int fra = wm*64 + (lane & 15);
    int frb = wn*64 + (lane & 15);
    int ks  = lane >> 4;

    f32x4 acc[4][4];
    #pragma unroll
    for (int i = 0; i < 4; ++i)
        #pragma unroll
        for (int j = 0; j < 4; ++j) acc[i][j] = (f32x4){0.f, 0.f, 0.f, 0.f};

    for (int kt = 0; kt < 8; ++kt) {
        int k0 = kt * 32;
        gload16(th + ga0 + k0, &lds[0][o0]);
        gload16(th + ga1 + k0, &lds[0][o1]);
        gload16(tl + ga0 + k0, &lds[1][o0]);
        gload16(tl + ga1 + k0, &lds[1][o1]);
        gload16(ph + gb0 + k0, &lds[2][o0]);
        gload16(ph + gb1 + k0, &lds[2][o1]);
        gload16(pl + gb0 + k0, &lds[3][o0]);
        gload16(pl + gb1 + k0, &lds[3][o1]);
        __syncthreads();

        f16x8 ah[4], al[4], bh[4], bl[4];
        #pragma unroll
        for (int i = 0; i < 4; ++i) {
            int rowa = fra + i*16;
            int offa = rowa*64 + ((ks ^ ((rowa >> 1) & 3)) << 4);
            ah[i] = *(const f16x8*)&lds[0][offa];
            al[i] = *(const f16x8*)&lds[1][offa];
            int rowb = frb + i*16;
            int offb = rowb*64 + ((ks ^ ((rowb >> 1) & 3)) << 4);
            bh[i] = *(const f16x8*)&lds[2][offb];
            bl[i] = *(const f16x8*)&lds[3][offb];
        }
        #pragma unroll
        for (int i = 0; i < 4; ++i)
            #pragma unroll
            for (int j = 0; j < 4; ++j) {
                acc[i][j] = __builtin_amdgcn_mfma_f32_16x16x32_f16(ah[i], bh[j], acc[i][j], 0, 0, 0);
                acc[i][j] = __builtin_amdgcn_mfma_f32_16x16x32_f16(ah[i], bl[j], acc[i][j], 0, 0, 0);
                acc[i][j] = __builtin_amdgcn_mfma_f32_16x16x32_f16(al[i], bh[j], acc[i][j], 0, 0, 0);
            }
        __syncthreads();
    }

    const float* rnx = rnorms + (size_t)b * HW;
    const float* rny = rnorms + (size_t)(NB + b) * HW;
    int colb = n0 + wn*64 + (lane & 15);
    int rowb = m0 + wm*64 + (lane >> 4) * 4;
    #pragma unroll
    for (int j = 0; j < 4; ++j) {
        int col = colb + j*16;
        float ry = rny[col];
        #pragma unroll
        for (int i = 0; i < 4; ++i) {
            int row = rowb + i*16;
            #pragma unroll
            for (int r = 0; r < 4; ++r)
                f[(size_t)(row + r)*HW + col] = acc[i][j][r] * rnx[row + r] * ry;
        }
    }
}

// per-row: max, 1/sum(exp), coords, attn — one block per row
__global__ __launch_bounds__(256) void row_stats_kernel(const float* __restrict__ f,
        const float* __restrict__ yi, float* __restrict__ rmax, float* __restrict__ rsuminv,
        float* __restrict__ coords, float* __restrict__ attn, int b) {
    __shared__ float row[HW];
    __shared__ float red[256];
    __shared__ float red6[6][256];
    int m = blockIdx.x, tid = threadIdx.x;
    const float* fr = f + (size_t)m * HW;
    float lmax = -3.0e38f;
    for (int i = tid; i < HW; i += 256) { float v = fr[i]; row[i] = v; lmax = fmaxf(lmax, v); }
    red[tid] = lmax; __syncthreads();
    for (int st = 128; st > 0; st >>= 1) {
        if (tid < st) red[tid] = fmaxf(red[tid], red[tid+st]);
        __syncthreads();
    }
    float rm = red[0];
    const float* yib = yi + (size_t)b * 3 * HW;
    float s=0, cx=0, cy=0, a0=0, a1=0, a2=0;
    for (int i = tid; i < HW; i += 256) {
        float e = __expf((row[i] - rm) * INV_T);
        s  += e;
        cx += e * (float)(i & 63);
        cy += e * (float)(i >> 6);
        a0 += e * yib[i];
        a1 += e * yib[HW + i];
        a2 += e * yib[2*HW + i];
    }
    red6[0][tid]=s; red6[1][tid]=cx; red6[2][tid]=cy;
    red6[3][tid]=a0; red6[4][tid]=a1; red6[5][tid]=a2;
    __syncthreads();
    for (int st = 128; st > 0; st >>= 1) {
        if (tid < st)
            for (int c = 0; c < 6; ++c) red6[c][tid] += red6[c][tid+st];
        __syncthreads();
    }
    if (tid == 0) {
        float inv = 1.0f / red6[0][0];
        rmax[m] = rm; rsuminv[m] = inv;
        coords[((size_t)b*2 + 0)*HW + m] = red6[1][0] * inv;
        coords[((size_t)b*2 + 1)*HW + m] = red6[2][0] * inv;
        attn[((size_t)b*HW + m)*3 + 0] = red6[3][0] * inv;
        attn[((size_t)b*HW + m)*3 + 1] = red6[4][0] * inv;
        attn[((size_t)b*HW + m)*3 + 2] = red6[5][0] * inv;
    }
}

__global__ void col_partial_kernel(const float* __restrict__ f,
                                   float* __restrict__ pmax, float* __restrict__ psum) {
    int n  = blockIdx.x * 256 + threadIdx.x;
    int j0 = blockIdx.y * 512;
    float mx = -3.0e38f, s = 0.f;
    for (int j = j0; j < j0 + 512; ++j) {
        float v  = f[(size_t)j * HW + n];
        float nm = fmaxf(mx, v);
        s = s * __expf((mx - nm) * INV_T) + __expf((v - nm) * INV_T);
        mx = nm;
    }
    pmax[(size_t)blockIdx.y * HW + n] = mx;
    psum[(size_t)blockIdx.y * HW + n] = s;
}

__global__ void col_combine_kernel(const float* __restrict__ pmax, const float* __restrict__ psum,
                                   float* __restrict__ cmax, float* __restrict__ csuminv) {
    int n = blockIdx.x * 256 + threadIdx.x;
    float mx = -3.0e38f;
    for (int k = 0; k < 8; ++k) mx = fmaxf(mx, pmax[(size_t)k*HW + n]);
    float s = 0.f;
    for (int k = 0; k < 8; ++k)
        s += psum[(size_t)k*HW + n] * __expf((pmax[(size_t)k*HW + n] - mx) * INV_T);
    cmax[n] = mx;
    csuminv[n] = 1.0f / s;
}

// y partials: MFMA f16. P recomputed from f on the fly (A), yf16 as B.
// tile: 128 m x 256 c, BK=32, 8 waves (2m x 4c), split-K: grid (32 m-tiles, 8 ks)
__global__ __launch_bounds__(512) void gemm_y_kernel(const float* __restrict__ f,
        const float* __restrict__ rmax, const _Float16* __restrict__ yf16,
        float* __restrict__ yp, int b) {
    __shared__ __align__(16) char ldsA[8192];    // P tile [128 m][32 k] f16, 64B rows
    __shared__ __align__(16) char ldsB[16384];   // Y tile [256 c][32 k] f16, 64B rows
    int tid  = threadIdx.x;
    int lane = tid & 63;
    int w = tid >> 6, wm = w >> 2, wn = w & 3;
    int m0 = blockIdx.x * 128;
    int ks = blockIdx.y;
    const _Float16* Yb = yf16 + (size_t)b * NCH * HW;

    // A staging: thread -> (row = tid>>2, k-chunk kc = tid&3); swizzled LDS slot
    int ar = tid >> 2, akc = tid & 3;
    int aoff = ar*64 + ((akc ^ ((ar >> 1) & 3)) << 4);
    float arm = rmax[m0 + ar];
    const float* frow = f + (size_t)(m0 + ar)*HW + akc*8;

    // B staging via global_load_lds: two lane-linear 16B chunks, pre-swizzled source
    int o0 = tid*16, o1 = o0 + 8192;
    int br0 = o0 >> 6, bs0 = (o0 >> 4) & 3, bg0 = bs0 ^ ((br0 >> 1) & 3);
    int br1 = o1 >> 6, bs1 = (o1 >> 4) & 3, bg1 = bs1 ^ ((br1 >> 1) & 3);
    size_t gb0 = (size_t)br0*HW + bg0*8;
    size_t gb1 = (size_t)br1*HW + bg1*8;

    int fra = wm*64 + (lane & 15);   // m-fragment rows
    int frb = wn*64 + (lane & 15);   // c-fragment rows
    int kslot = lane >> 4;

    f32x4 acc[4][4];
    #pragma unroll
    for (int i = 0; i < 4; ++i)
        #pragma unroll
        for (int j = 0; j < 4; ++j) acc[i][j] = (f32x4){0.f, 0.f, 0.f, 0.f};

    for (int k0 = ks*512; k0 < ks*512 + 512; k0 += 32) {
        gload16(Yb + gb0 + k0, &ldsB[o0]);
        gload16(Yb + gb1 + k0, &ldsB[o1]);
        const float4* fp = (const float4*)(frow + k0);
        float4 v0 = fp[0], v1 = fp[1];
        f16x8 pk;
        pk[0] = (_Float16)__expf((v0.x - arm) * INV_T);
        pk[1] = (_Float16)__expf((v0.y - arm) * INV_T);
        pk[2] = (_Float16)__expf((v0.z - arm) * INV_T);
        pk[3] = (_Float16)__expf((v0.w - arm) * INV_T);
        pk[4] = (_Float16)__expf((v1.x - arm) * INV_T);
        pk[5] = (_Float16)__expf((v1.y - arm) * INV_T);
        pk[6] = (_Float16)__expf((v1.z - arm) * INV_T);
        pk[7] = (_Float16)__expf((v1.w - arm) * INV_T);
        *(f16x8*)&ldsA[aoff] = pk;
        __syncthreads();

        f16x8 af[4], bf[4];
        #pragma unroll
        for (int i = 0; i < 4; ++i) {
            int rowa = fra + i*16;
            af[i] = *(const f16x8*)&ldsA[rowa*64 + ((kslot ^ ((rowa >> 1) & 3)) << 4)];
            int rowb = frb + i*16;
            bf[i] = *(const f16x8*)&ldsB[rowb*64 + ((kslot ^ ((rowb >> 1) & 3)) << 4)];
        }
        #pragma unroll
        for (int i = 0; i < 4; ++i)
            #pragma unroll
            for (int j = 0; j < 4; ++j)
                acc[i][j] = __builtin_amdgcn_mfma_f32_16x16x32_f16(af[i], bf[j], acc[i][j], 0, 0, 0);
        __syncthreads();
    }

    #pragma unroll
    for (int i = 0; i < 4; ++i) {
        int m = m0 + wm*64 + i*16 + (lane >> 4) * 4;
        #pragma unroll
        for (int j = 0; j < 4; ++j) {
            int c = wn*64 + j*16 + (lane & 15);
            *(f32x4*)(yp + ((size_t)ks*NCH + c)*HW + m) = acc[i][j];
        }
    }
}

__global__ void ycombine_kernel(const float* __restrict__ yp, const float* __restrict__ rsuminv,
                                float* __restrict__ out, int b) {
    size_t idx = (size_t)blockIdx.x * 256 + threadIdx.x;
    int m = (int)(idx & (HW - 1));
    float s = 0.f;
    #pragma unroll
    for (int k = 0; k < 8; ++k) s += yp[(size_t)k*NCH*HW + idx];
    out[OUT_Y + (size_t)b*NCH*HW + idx] = s * rsuminv[m];
}

__global__ __launch_bounds__(256) void cyc_partial_kernel(const float* __restrict__ f,
        const float* __restrict__ cmax, const float* __restrict__ attn,
        float* __restrict__ part, int b) {
    __shared__ float at[512*3];
    int i  = blockIdx.x * 256 + threadIdx.x;
    int j0 = blockIdx.y * 512;
    for (int k = threadIdx.x; k < 1536; k += 256)
        at[k] = attn[((size_t)b*HW + j0)*3 + k];
    __syncthreads();
    float cm = cmax[i];
    float a0=0, a1=0, a2=0;
    for (int jj = 0; jj < 512; ++jj) {
        float e = __expf((f[(size_t)(j0+jj)*HW + i] - cm) * INV_T);
        a0 = fmaf(e, at[jj*3+0], a0);
        a1 = fmaf(e, at[jj*3+1], a1);
        a2 = fmaf(e, at[jj*3+2], a2);
    }
    part[((size_t)blockIdx.y*3 + 0)*HW + i] = a0;
    part[((size_t)blockIdx.y*3 + 1)*HW + i] = a1;
    part[((size_t)blockIdx.y*3 + 2)*HW + i] = a2;
}

__global__ void cyc_combine_kernel(const float* __restrict__ part, const float* __restrict__ csuminv,
                                   float* __restrict__ cyc, int b) {
    int i = blockIdx.x * 256 + threadIdx.x;
    int c = blockIdx.y;
    float s = 0.f;
    for (int k = 0; k < 8; ++k) s += part[((size_t)k*3 + c)*HW + i];
    cyc[((size_t)b*3 + c)*HW + i] = s * csuminv[i];
}

__global__ void flow_kernel(const float* __restrict__ coords, float* __restrict__ out) {
    size_t idx = (size_t)blockIdx.x * 256 + threadIdx.x;
    int x4 = (int)(idx & 255);
    int y4 = (int)((idx >> 8) & 255);
    int ch = (int)((idx >> 16) & 1);
    int b  = (int)(idx >> 17);
    int w = x4 >> 2, h = y4 >> 2;
    int m = h*64 + w;
    float c1 = coords[((size_t)b*2 + ch)*HW + m];
    float c0 = (ch == 0) ? (float)w : (float)h;
    out[OUT_FLOW + idx] = c1 - c0;
}

__global__ void imgout_kernel(const float* __restrict__ attn, const float* __restrict__ cyc,
                              float* __restrict__ out) {
    size_t idx = (size_t)blockIdx.x * 256 + threadIdx.x;
    int x4 = (int)(idx & 255);
    int y4 = (int)((idx >> 8) & 255);
    int rest = (int)(idx >> 16);
    int ch = rest % 3, b = rest / 3;
    int m = (y4 >> 2)*64 + (x4 >> 2);
    out[OUT_IMG  + idx] = attn[((size_t)b*HW + m)*3 + ch];
    out[OUT_CYCO + idx] = cyc[((size_t)b*3 + ch)*HW + m];
}

__global__ void loss_partial_kernel(const float* __restrict__ xf, const float* __restrict__ yf,
                                    const float* __restrict__ means, const float* __restrict__ rnorms,
                                    float* __restrict__ part) {
    __shared__ float red[256];
    size_t base = (size_t)blockIdx.x * 4096;
    float s = 0.f;
    for (int k = 0; k < 16; ++k) {
        size_t id = base + (size_t)k*256 + threadIdx.x;
        int m  = (int)(id & (HW - 1));
        int bc = (int)(id >> 12);
        int b  = bc >> 8;
        float th = (xf[id] - means[bc])          * rnorms[(size_t)b*HW + m];
        float ph = (yf[id] - means[NB*NCH + bc]) * rnorms[(size_t)(NB + b)*HW + m];
        s += fabsf(th - ph);
    }
    red[threadIdx.x] = s; __syncthreads();
    for (int st = 128; st > 0; st >>= 1) {
        if (threadIdx.x < st) red[threadIdx.x] += red[threadIdx.x + st];
        __syncthreads();
    }
    if (threadIdx.x == 0) part[blockIdx.x] = red[0];
}

__global__ void loss_final_kernel(const float* __restrict__ part, float* __restrict__ out) {
    __shared__ float red[256];
    float s = 0.f;
    for (int k = threadIdx.x; k < 1024; k += 256) s += part[k];
    red[threadIdx.x] = s; __syncthreads();
    for (int st = 128; st > 0; st >>= 1) {
        if (threadIdx.x < st) red[threadIdx.x] += red[threadIdx.x + st];
        __syncthreads();
    }
    if (threadIdx.x == 0) out[OUT_LOSS] = red[0] * (1.0f / 4194304.0f);
}

extern "C" void kernel_launch(void* const* d_in, const int* in_sizes, int n_in,
                              void* d_out, int out_size, void* d_ws, size_t ws_size,
                              hipStream_t stream) {
    (void)in_sizes; (void)n_in; (void)out_size; (void)ws_size;
    const float* xf   = (const float*)d_in[0];
    const float* yf   = (const float*)d_in[1];
    const float* yimg = (const float*)d_in[2];
    float* out = (float*)d_out;
    float* ws  = (float*)d_ws;

    _Float16* yf16 = (_Float16*)(ws + OFF_YT);
    float* yi      = ws + OFF_YI;
    float* means   = ws + OFF_MEAN;
    float* rnorms  = ws + OFF_RNORM;
    float* nsqp    = ws + OFF_NSQP;
    float* fbuf    = ws + OFF_F;
    float* yp      = ws + OFF_YP;
    float* rmax    = ws + OFF_RMAX;
    float* rsuminv = ws + OFF_RSUM;
    float* cmax    = ws + OFF_CMAX;
    float* csuminv = ws + OFF_CSUM;
    float* cpm     = ws + OFF_CPM;
    float* cps     = ws + OFF_CPS;
    float* coords  = ws + OFF_COORD;
    float* attn    = ws + OFF_ATTN;
    float* cyc     = ws + OFF_CYC;
    float* cycp    = ws + OFF_CYCP;
    float* lossp   = ws + OFF_LOSSP;
    _Float16* th = (_Float16*)(ws + OFF_F16);
    _Float16* tl = th + (size_t)HW*NCH;
    _Float16* ph = tl + (size_t)HW*NCH;
    _Float16* pl = ph + (size_t)HW*NCH;

    mean_kernel        <<<dim3(NB*NCH, 2),   256, 0, stream>>>(xf, yf, means);
    nsq_partial_kernel <<<dim3(16, 8, 8),    256, 0, stream>>>(xf, yf, means, nsqp);
    nsq_combine_kernel <<<dim3(16, 8),       256, 0, stream>>>(nsqp, rnorms);
    ycast_kernel       <<<2048,              256, 0, stream>>>(yf, yf16);
    avgpool_kernel     <<<NB*3*HW/256,       256, 0, stream>>>(yimg, yi);

    for (int b = 0; b < NB; ++b) {
        prep_kernel        <<<dim3(8, 128, 2), 256, 0, stream>>>(xf, yf, means, th, tl, ph, pl, b);
        gemm_f_kernel      <<<dim3(32, 32),    256, 0, stream>>>(th, tl, ph, pl, rnorms, fbuf, b);
        row_stats_kernel   <<<HW,              256, 0, stream>>>(fbuf, yi, rmax, rsuminv, coords, attn, b);
        col_partial_kernel <<<dim3(16, 8),     256, 0, stream>>>(fbuf, cpm, cps);
        col_combine_kernel <<<16,              256, 0, stream>>>(cpm, cps, cmax, csuminv);
        gemm_y_kernel      <<<dim3(32, 8),     512, 0, stream>>>(fbuf, rmax, yf16, yp, b);
        ycombine_kernel    <<<NCH*HW/256,      256, 0, stream>>>(yp, rsuminv, out, b);
        cyc_partial_kernel <<<dim3(16, 8),     256, 0, stream>>>(fbuf, cmax, attn, cycp, b);
        cyc_combine_kernel <<<dim3(16, 3),     256, 0, stream>>>(cycp, csuminv, cyc, b);
    }

    flow_kernel        <<<NB*2*65536/256, 256, 0, stream>>>(coords, out);
    imgout_kernel      <<<NB*3*65536/256, 256, 0, stream>>>(attn, cyc, out);
    loss_partial_kernel<<<1024,           256, 0, stream>>>(xf, yf, means, rnorms, lossp);
    loss_final_kernel  <<<1,              256, 0, stream>>>(lossp, out);
}

// Round 5
// 552.028 us; speedup vs baseline: 5.2865x; 1.4028x over previous
//
#include <hip/hip_runtime.h>
#include <math.h>

#define HW   4096
#define NCH  256
#define NB   4

constexpr float TEMP  = (float)(0.0001 * 5.0);
constexpr float INV_T = 1.0f / TEMP;
constexpr float EPSN  = 2.220446049250313e-16f;

typedef __attribute__((ext_vector_type(8))) _Float16 f16x8;
typedef __attribute__((ext_vector_type(4))) float    f32x4;

// ---------------- workspace layout (in floats) ----------------
constexpr size_t OFF_YT    = 0;                                 // yf16: NB*HW*NCH f16
constexpr size_t OFF_YI    = OFF_YT    + (size_t)NB*HW*NCH;     // NB*3*HW
constexpr size_t OFF_MEAN  = OFF_YI    + (size_t)NB*3*HW;       // 2*NB*NCH
constexpr size_t OFF_RNORM = OFF_MEAN  + (size_t)2*NB*NCH;      // 2*NB*HW
constexpr size_t OFF_NSQP  = OFF_RNORM + (size_t)2*NB*HW;       // 2*NB*8*HW
constexpr size_t OFF_F     = OFF_NSQP  + (size_t)2*NB*8*HW;     // HW*HW
constexpr size_t OFF_YP    = OFF_F     + (size_t)HW*HW;         // 8*NCH*HW (split-K partials)
// rowp/colp ALIAS the yp buffer: they are consumed (row/col combine) before
// gemm_y writes yp. rowp: [32 ntile][7][HW]; colp: [32 mtile][2][HW]
constexpr size_t OFF_ROWP  = OFF_YP;                            // 917504
constexpr size_t OFF_COLP  = OFF_YP + (size_t)32*7*HW;          // 262144
constexpr size_t OFF_RMAX  = OFF_YP    + (size_t)8*NCH*HW;
constexpr size_t OFF_RSUM  = OFF_RMAX  + HW;
constexpr size_t OFF_CMAX  = OFF_RSUM  + HW;
constexpr size_t OFF_CSUM  = OFF_CMAX  + HW;
constexpr size_t OFF_COORD = OFF_CSUM  + HW;                // NB*2*HW
constexpr size_t OFF_ATTN  = OFF_COORD + (size_t)NB*2*HW;   // NB*HW*3
constexpr size_t OFF_CYC   = OFF_ATTN  + (size_t)NB*HW*3;   // NB*3*HW
constexpr size_t OFF_CYCP  = OFF_CYC   + (size_t)NB*3*HW;   // 32*3*HW
constexpr size_t OFF_LOSSP = OFF_CYCP  + (size_t)32*3*HW;   // 1024
constexpr size_t OFF_F16   = OFF_LOSSP + 1024;              // 4 * 524288 floats

// ---------------- output layout (floats) ----------------
constexpr size_t OUT_Y    = 0;
constexpr size_t OUT_FLOW = (size_t)NB*NCH*HW;
constexpr size_t OUT_IMG  = OUT_FLOW + (size_t)NB*2*256*256;
constexpr size_t OUT_CYCO = OUT_IMG  + (size_t)NB*3*256*256;
constexpr size_t OUT_LOSS = OUT_CYCO + (size_t)NB*3*256*256;

__device__ __forceinline__ void gload16(const void* g, void* l) {
    __builtin_amdgcn_global_load_lds(
        (const __attribute__((address_space(1))) unsigned int*)g,
        (__attribute__((address_space(3))) unsigned int*)l, 16, 0, 0);
}

__global__ void mean_kernel(const float* __restrict__ xf, const float* __restrict__ yf,
                            float* __restrict__ means) {
    const float* src = (blockIdx.y == 0 ? xf : yf) + (size_t)blockIdx.x * HW;
    float s = 0.f;
    for (int i = threadIdx.x; i < HW; i += 256) s += src[i];
    __shared__ float red[256];
    red[threadIdx.x] = s; __syncthreads();
    for (int st = 128; st > 0; st >>= 1) {
        if (threadIdx.x < st) red[threadIdx.x] += red[threadIdx.x + st];
        __syncthreads();
    }
    if (threadIdx.x == 0) means[blockIdx.y * (NB*NCH) + blockIdx.x] = red[0] * (1.0f / HW);
}

__global__ void nsq_partial_kernel(const float* __restrict__ xf, const float* __restrict__ yf,
                                   const float* __restrict__ means, float* __restrict__ part) {
    int t = blockIdx.z >> 2, b = blockIdx.z & 3;
    int m = blockIdx.x * 256 + threadIdx.x;
    int c0 = blockIdx.y * 32;
    const float* src = (t == 0 ? xf : yf) + (size_t)b * NCH * HW;
    const float* mn = means + t * (NB*NCH) + b * NCH;
    float acc = 0.f;
    for (int c = c0; c < c0 + 32; ++c) {
        float v = src[(size_t)c * HW + m] - mn[c];
        acc += v * v;
    }
    part[(((size_t)t*NB + b) * 8 + blockIdx.y) * HW + m] = acc;
}

__global__ void nsq_combine_kernel(const float* __restrict__ part, float* __restrict__ rnorms) {
    int t = blockIdx.y >> 2, b = blockIdx.y & 3;
    int m = blockIdx.x * 256 + threadIdx.x;
    const float* p = part + ((size_t)t*NB + b) * 8 * HW + m;
    float s = 0.f;
    for (int k = 0; k < 8; ++k) s += p[(size_t)k * HW];
    rnorms[((size_t)t*NB + b) * HW + m] = 1.0f / (sqrtf(s) + EPSN);
}

__global__ void ycast_kernel(const float* __restrict__ yf, _Float16* __restrict__ yf16) {
    size_t i = ((size_t)blockIdx.x * 256 + threadIdx.x) * 8;
    const float4* s = (const float4*)(yf + i);
    float4 v0 = s[0], v1 = s[1];
    f16x8 o;
    o[0]=(_Float16)v0.x; o[1]=(_Float16)v0.y; o[2]=(_Float16)v0.z; o[3]=(_Float16)v0.w;
    o[4]=(_Float16)v1.x; o[5]=(_Float16)v1.y; o[6]=(_Float16)v1.z; o[7]=(_Float16)v1.w;
    *(f16x8*)(yf16 + i) = o;
}

__global__ void prep_kernel(const float* __restrict__ xf, const float* __restrict__ yf,
                            const float* __restrict__ means,
                            _Float16* __restrict__ th, _Float16* __restrict__ tl,
                            _Float16* __restrict__ ph, _Float16* __restrict__ pl, int b) {
    __shared__ float tile[32][33];
    int t = blockIdx.z;
    int c0 = blockIdx.x * 32, m0 = blockIdx.y * 32;
    const float* src = (t == 0 ? xf : yf) + (size_t)b * NCH * HW;
    const float* mn  = means + t * (NB*NCH) + b * NCH;
    int tx = threadIdx.x & 31, ty = threadIdx.x >> 5;
    for (int i = ty; i < 32; i += 8)
        tile[i][tx] = src[(size_t)(c0 + i) * HW + m0 + tx] - mn[c0 + i];
    __syncthreads();
    _Float16* H = (t == 0 ? th : ph);
    _Float16* L = (t == 0 ? tl : pl);
    for (int i = ty; i < 32; i += 8) {
        float v = tile[tx][i];
        _Float16 h = (_Float16)v;
        _Float16 l = (_Float16)(v - (float)h);
        H[(size_t)(m0 + i)*NCH + c0 + tx] = h;
        L[(size_t)(m0 + i)*NCH + c0 + tx] = l;
    }
}

__global__ void avgpool_kernel(const float* __restrict__ yimg, float* __restrict__ yi) {
    size_t idx = (size_t)blockIdx.x * 256 + threadIdx.x;
    int m  = (int)(idx & (HW - 1));
    int bc = (int)(idx >> 12);
    int h = m >> 6, w = m & 63;
    const float* p = yimg + (size_t)bc * 65536 + (size_t)(h*4) * 256 + w*4;
    float s = 0.f;
    #pragma unroll
    for (int dy = 0; dy < 4; ++dy) {
        #pragma unroll
        for (int dx = 0; dx < 4; ++dx) s += p[dy*256 + dx];
    }
    yi[idx] = s * (1.0f/16.0f);
}

// f = (hi+lo)x(hi+lo) MFMA GEMM, 128x128 tile, BK=32, 4 waves.
// Epilogue: writes f AND per-tile row partials (max + 6 exp-weighted sums)
// and col partials (max + exp-sum) via deterministic shuffle/LDS trees.
__global__ __launch_bounds__(256) void gemm_f_kernel(
        const _Float16* __restrict__ th, const _Float16* __restrict__ tl,
        const _Float16* __restrict__ ph, const _Float16* __restrict__ pl,
        const float* __restrict__ rnorms, const float* __restrict__ yi,
        float* __restrict__ f, float* __restrict__ rowp, float* __restrict__ colp,
        int b) {
    __shared__ char lds[4][8192];
    int tid  = threadIdx.x;
    int lane = tid & 63;
    int w = tid >> 6, wm = w >> 1, wn = w & 1;
    int m0 = blockIdx.y * 128, n0 = blockIdx.x * 128;

    int o0 = tid * 16, o1 = o0 + 4096;
    int r0 = o0 >> 6, s0 = (o0 >> 4) & 3, g0 = s0 ^ ((r0 >> 1) & 3);
    int r1 = o1 >> 6, s1 = (o1 >> 4) & 3, g1 = s1 ^ ((r1 >> 1) & 3);
    size_t ga0 = (size_t)(m0 + r0)*NCH + g0*8;
    size_t ga1 = (size_t)(m0 + r1)*NCH + g1*8;
    size_t gb0 = (size_t)(n0 + r0)*NCH + g0*8;
    size_t gb1 = (size_t)(n0 + r1)*NCH + g1*8;

    int fra = wm*64 + (lane & 15);
    int frb = wn*64 + (lane & 15);
    int ks  = lane >> 4;

    f32x4 acc[4][4];
    #pragma unroll
    for (int i = 0; i < 4; ++i)
        #pragma unroll
        for (int j = 0; j < 4; ++j) acc[i][j] = (f32x4){0.f, 0.f, 0.f, 0.f};

    for (int kt = 0; kt < 8; ++kt) {
        int k0 = kt * 32;
        gload16(th + ga0 + k0, &lds[0][o0]);
        gload16(th + ga1 + k0, &lds[0][o1]);
        gload16(tl + ga0 + k0, &lds[1][o0]);
        gload16(tl + ga1 + k0, &lds[1][o1]);
        gload16(ph + gb0 + k0, &lds[2][o0]);
        gload16(ph + gb1 + k0, &lds[2][o1]);
        gload16(pl + gb0 + k0, &lds[3][o0]);
        gload16(pl + gb1 + k0, &lds[3][o1]);
        __syncthreads();

        f16x8 ah[4], al[4], bh[4], bl[4];
        #pragma unroll
        for (int i = 0; i < 4; ++i) {
            int rowa = fra + i*16;
            int offa = rowa*64 + ((ks ^ ((rowa >> 1) & 3)) << 4);
            ah[i] = *(const f16x8*)&lds[0][offa];
            al[i] = *(const f16x8*)&lds[1][offa];
            int rowb = frb + i*16;
            int offb = rowb*64 + ((ks ^ ((rowb >> 1) & 3)) << 4);
            bh[i] = *(const f16x8*)&lds[2][offb];
            bl[i] = *(const f16x8*)&lds[3][offb];
        }
        #pragma unroll
        for (int i = 0; i < 4; ++i)
            #pragma unroll
            for (int j = 0; j < 4; ++j) {
                acc[i][j] = __builtin_amdgcn_mfma_f32_16x16x32_f16(ah[i], bh[j], acc[i][j], 0, 0, 0);
                acc[i][j] = __builtin_amdgcn_mfma_f32_16x16x32_f16(ah[i], bl[j], acc[i][j], 0, 0, 0);
                acc[i][j] = __builtin_amdgcn_mfma_f32_16x16x32_f16(al[i], bh[j], acc[i][j], 0, 0, 0);
            }
        __syncthreads();
    }

    // ---- scale acc in place: f_val = acc * rnx[row] * rny[col] ----
    const float* rnx = rnorms + (size_t)b * HW;
    const float* rny = rnorms + (size_t)(NB + b) * HW;
    int colg[4];
    float ryv[4];
    #pragma unroll
    for (int j = 0; j < 4; ++j) {
        colg[j] = n0 + wn*64 + j*16 + (lane & 15);
        ryv[j] = rny[colg[j]];
    }
    #pragma unroll
    for (int i = 0; i < 4; ++i) {
        int rb = m0 + wm*64 + i*16 + (lane >> 4)*4;
        #pragma unroll
        for (int r = 0; r < 4; ++r) {
            float rx = rnx[rb + r];
            #pragma unroll
            for (int j = 0; j < 4; ++j)
                acc[i][j][r] *= rx * ryv[j];
        }
    }
    // ---- write f ----
    #pragma unroll
    for (int j = 0; j < 4; ++j)
        #pragma unroll
        for (int i = 0; i < 4; ++i) {
            int rb = m0 + wm*64 + i*16 + (lane >> 4)*4;
            #pragma unroll
            for (int r = 0; r < 4; ++r)
                f[(size_t)(rb + r)*HW + colg[j]] = acc[i][j][r];
        }

    // ---- partial stats (deterministic trees) ----
    float* rmaxw = (float*)&lds[0][0];   // [2 wn][128 row]
    float* sums6 = rmaxw + 256;          // [2 wn][128 row][6]
    float* colmw = sums6 + 1536;         // [2 wm][128 col]
    float* colsw = colmw + 256;          // [2 wm][128 col]

    // step 1: wave-level maxes
    float rm[4][4];
    #pragma unroll
    for (int i = 0; i < 4; ++i)
        #pragma unroll
        for (int r = 0; r < 4; ++r) {
            float v = fmaxf(fmaxf(acc[0*0+i][0][r], acc[i][1][r]),
                            fmaxf(acc[i][2][r], acc[i][3][r]));
            #pragma unroll
            for (int d = 1; d < 16; d <<= 1) v = fmaxf(v, __shfl_xor(v, d));
            rm[i][r] = v;
        }
    if ((lane & 15) == 0) {
        #pragma unroll
        for (int i = 0; i < 4; ++i)
            #pragma unroll
            for (int r = 0; r < 4; ++r)
                rmaxw[wn*128 + wm*64 + i*16 + (lane >> 4)*4 + r] = rm[i][r];
    }
    float cmj[4];
    #pragma unroll
    for (int j = 0; j < 4; ++j) {
        float v = -3.0e38f;
        #pragma unroll
        for (int i = 0; i < 4; ++i)
            #pragma unroll
            for (int r = 0; r < 4; ++r) v = fmaxf(v, acc[i][j][r]);
        v = fmaxf(v, __shfl_xor(v, 16));
        v = fmaxf(v, __shfl_xor(v, 32));
        cmj[j] = v;
    }
    if ((lane >> 4) == 0) {
        #pragma unroll
        for (int j = 0; j < 4; ++j)
            colmw[wm*128 + wn*64 + j*16 + lane] = cmj[j];
    }
    __syncthreads();

    // step 2: exp sums relative to BLOCK maxes
    const float* yib = yi + (size_t)b * 3 * HW;
    float xcj[4], ycj[4], y0j[4], y1j[4], y2j[4];
    #pragma unroll
    for (int j = 0; j < 4; ++j) {
        xcj[j] = (float)(colg[j] & 63);
        ycj[j] = (float)(colg[j] >> 6);
        y0j[j] = yib[colg[j]];
        y1j[j] = yib[HW + colg[j]];
        y2j[j] = yib[2*HW + colg[j]];
    }
    #pragma unroll
    for (int i = 0; i < 4; ++i)
        #pragma unroll
        for (int r = 0; r < 4; ++r) {
            int rl = wm*64 + i*16 + (lane >> 4)*4 + r;
            float bm = fmaxf(rmaxw[rl], rmaxw[128 + rl]);
            float s=0, cx=0, cy=0, a0=0, a1=0, a2=0;
            #pragma unroll
            for (int j = 0; j < 4; ++j) {
                float e = __expf((acc[i][j][r] - bm) * INV_T);
                s += e; cx += e*xcj[j]; cy += e*ycj[j];
                a0 += e*y0j[j]; a1 += e*y1j[j]; a2 += e*y2j[j];
            }
            #pragma unroll
            for (int d = 1; d < 16; d <<= 1) {
                s  += __shfl_xor(s, d);  cx += __shfl_xor(cx, d);
                cy += __shfl_xor(cy, d); a0 += __shfl_xor(a0, d);
                a1 += __shfl_xor(a1, d); a2 += __shfl_xor(a2, d);
            }
            if ((lane & 15) == 0) {
                float* p = &sums6[(wn*128 + rl)*6];
                p[0]=s; p[1]=cx; p[2]=cy; p[3]=a0; p[4]=a1; p[5]=a2;
            }
        }
    #pragma unroll
    for (int j = 0; j < 4; ++j) {
        int cl = wn*64 + j*16 + (lane & 15);
        float cm = fmaxf(colmw[cl], colmw[128 + cl]);
        float cs = 0.f;
        #pragma unroll
        for (int i = 0; i < 4; ++i)
            #pragma unroll
            for (int r = 0; r < 4; ++r)
                cs += __expf((acc[i][j][r] - cm) * INV_T);
        cs += __shfl_xor(cs, 16);
        cs += __shfl_xor(cs, 32);
        if ((lane >> 4) == 0) colsw[wm*128 + cl] = cs;
    }
    __syncthreads();

    // step 3: global partial writes
    if (tid < 128) {
        int rl = tid;
        float bm = fmaxf(rmaxw[rl], rmaxw[128 + rl]);
        rowp[((size_t)blockIdx.x*7 + 0)*HW + m0 + rl] = bm;
        #pragma unroll
        for (int q = 0; q < 6; ++q)
            rowp[((size_t)blockIdx.x*7 + 1 + q)*HW + m0 + rl] =
                sums6[rl*6 + q] + sums6[(128 + rl)*6 + q];
    } else {
        int cl = tid - 128;
        float cm = fmaxf(colmw[cl], colmw[128 + cl]);
        colp[((size_t)blockIdx.y*2 + 0)*HW + n0 + cl] = cm;
        colp[((size_t)blockIdx.y*2 + 1)*HW + n0 + cl] = colsw[cl] + colsw[128 + cl];
    }
}

// combine 32 n-tile row partials -> rmax, rsuminv, coords, attn
__global__ void row_combine_kernel(const float* __restrict__ rowp,
        float* __restrict__ rmax, float* __restrict__ rsuminv,
        float* __restrict__ coords, float* __restrict__ attn, int b) {
    int m = blockIdx.x * 256 + threadIdx.x;
    float gm = -3.0e38f;
    for (int t = 0; t < 32; ++t) gm = fmaxf(gm, rowp[((size_t)t*7)*HW + m]);
    float S=0, CX=0, CY=0, A0=0, A1=0, A2=0;
    for (int t = 0; t < 32; ++t) {
        const float* p = rowp + (size_t)t*7*HW + m;
        float wgt = __expf((p[0] - gm) * INV_T);
        S  += p[1*HW] * wgt; CX += p[2*HW] * wgt; CY += p[3*HW] * wgt;
        A0 += p[4*HW] * wgt; A1 += p[5*HW] * wgt; A2 += p[6*HW] * wgt;
    }
    float inv = 1.0f / S;
    rmax[m] = gm; rsuminv[m] = inv;
    coords[((size_t)b*2 + 0)*HW + m] = CX * inv;
    coords[((size_t)b*2 + 1)*HW + m] = CY * inv;
    attn[((size_t)b*HW + m)*3 + 0] = A0 * inv;
    attn[((size_t)b*HW + m)*3 + 1] = A1 * inv;
    attn[((size_t)b*HW + m)*3 + 2] = A2 * inv;
}

// combine 32 m-tile col partials -> cmax, csuminv
__global__ void col_combine_kernel(const float* __restrict__ colp,
        float* __restrict__ cmax, float* __restrict__ csuminv) {
    int n = blockIdx.x * 256 + threadIdx.x;
    float gm = -3.0e38f;
    for (int t = 0; t < 32; ++t) gm = fmaxf(gm, colp[((size_t)t*2)*HW + n]);
    float S = 0.f;
    for (int t = 0; t < 32; ++t) {
        const float* p = colp + (size_t)t*2*HW + n;
        S += p[1*HW] * __expf((p[0] - gm) * INV_T);
    }
    cmax[n] = gm;
    csuminv[n] = 1.0f / S;
}

// y partials: MFMA f16. P recomputed from f on the fly (A), yf16 as B.
__global__ __launch_bounds__(512) void gemm_y_kernel(const float* __restrict__ f,
        const float* __restrict__ rmax, const _Float16* __restrict__ yf16,
        float* __restrict__ yp, int b) {
    __shared__ __align__(16) char ldsA[8192];
    __shared__ __align__(16) char ldsB[16384];
    int tid  = threadIdx.x;
    int lane = tid & 63;
    int w = tid >> 6, wm = w >> 2, wn = w & 3;
    int m0 = blockIdx.x * 128;
    int ks = blockIdx.y;
    const _Float16* Yb = yf16 + (size_t)b * NCH * HW;

    int ar = tid >> 2, akc = tid & 3;
    int aoff = ar*64 + ((akc ^ ((ar >> 1) & 3)) << 4);
    float arm = rmax[m0 + ar];
    const float* frow = f + (size_t)(m0 + ar)*HW + akc*8;

    int o0 = tid*16, o1 = o0 + 8192;
    int br0 = o0 >> 6, bs0 = (o0 >> 4) & 3, bg0 = bs0 ^ ((br0 >> 1) & 3);
    int br1 = o1 >> 6, bs1 = (o1 >> 4) & 3, bg1 = bs1 ^ ((br1 >> 1) & 3);
    size_t gb0 = (size_t)br0*HW + bg0*8;
    size_t gb1 = (size_t)br1*HW + bg1*8;

    int fra = wm*64 + (lane & 15);
    int frb = wn*64 + (lane & 15);
    int kslot = lane >> 4;

    f32x4 acc[4][4];
    #pragma unroll
    for (int i = 0; i < 4; ++i)
        #pragma unroll
        for (int j = 0; j < 4; ++j) acc[i][j] = (f32x4){0.f, 0.f, 0.f, 0.f};

    for (int k0 = ks*512; k0 < ks*512 + 512; k0 += 32) {
        gload16(Yb + gb0 + k0, &ldsB[o0]);
        gload16(Yb + gb1 + k0, &ldsB[o1]);
        const float4* fp = (const float4*)(frow + k0);
        float4 v0 = fp[0], v1 = fp[1];
        f16x8 pk;
        pk[0] = (_Float16)__expf((v0.x - arm) * INV_T);
        pk[1] = (_Float16)__expf((v0.y - arm) * INV_T);
        pk[2] = (_Float16)__expf((v0.z - arm) * INV_T);
        pk[3] = (_Float16)__expf((v0.w - arm) * INV_T);
        pk[4] = (_Float16)__expf((v1.x - arm) * INV_T);
        pk[5] = (_Float16)__expf((v1.y - arm) * INV_T);
        pk[6] = (_Float16)__expf((v1.z - arm) * INV_T);
        pk[7] = (_Float16)__expf((v1.w - arm) * INV_T);
        *(f16x8*)&ldsA[aoff] = pk;
        __syncthreads();

        f16x8 af[4], bf[4];
        #pragma unroll
        for (int i = 0; i < 4; ++i) {
            int rowa = fra + i*16;
            af[i] = *(const f16x8*)&ldsA[rowa*64 + ((kslot ^ ((rowa >> 1) & 3)) << 4)];
            int rowb = frb + i*16;
            bf[i] = *(const f16x8*)&ldsB[rowb*64 + ((kslot ^ ((rowb >> 1) & 3)) << 4)];
        }
        #pragma unroll
        for (int i = 0; i < 4; ++i)
            #pragma unroll
            for (int j = 0; j < 4; ++j)
                acc[i][j] = __builtin_amdgcn_mfma_f32_16x16x32_f16(af[i], bf[j], acc[i][j], 0, 0, 0);
        __syncthreads();
    }

    #pragma unroll
    for (int i = 0; i < 4; ++i) {
        int m = m0 + wm*64 + i*16 + (lane >> 4) * 4;
        #pragma unroll
        for (int j = 0; j < 4; ++j) {
            int c = wn*64 + j*16 + (lane & 15);
            *(f32x4*)(yp + ((size_t)ks*NCH + c)*HW + m) = acc[i][j];
        }
    }
}

__global__ void ycombine_kernel(const float* __restrict__ yp, const float* __restrict__ rsuminv,
                                float* __restrict__ out, int b) {
    size_t idx = (size_t)blockIdx.x * 256 + threadIdx.x;
    int m = (int)(idx & (HW - 1));
    float s = 0.f;
    #pragma unroll
    for (int k = 0; k < 8; ++k) s += yp[(size_t)k*NCH*HW + idx];
    out[OUT_Y + (size_t)b*NCH*HW + idx] = s * rsuminv[m];
}

// cyc partial over row-chunks of 128 (512 blocks)
__global__ __launch_bounds__(256) void cyc_partial_kernel(const float* __restrict__ f,
        const float* __restrict__ cmax, const float* __restrict__ attn,
        float* __restrict__ part, int b) {
    __shared__ float at[128*3];
    int i  = blockIdx.x * 256 + threadIdx.x;
    int j0 = blockIdx.y * 128;
    for (int k = threadIdx.x; k < 384; k += 256)
        at[k] = attn[((size_t)b*HW + j0)*3 + k];
    __syncthreads();
    float cm = cmax[i];
    float a0=0, a1=0, a2=0;
    for (int jj = 0; jj < 128; ++jj) {
        float e = __expf((f[(size_t)(j0+jj)*HW + i] - cm) * INV_T);
        a0 = fmaf(e, at[jj*3+0], a0);
        a1 = fmaf(e, at[jj*3+1], a1);
        a2 = fmaf(e, at[jj*3+2], a2);
    }
    part[((size_t)blockIdx.y*3 + 0)*HW + i] = a0;
    part[((size_t)blockIdx.y*3 + 1)*HW + i] = a1;
    part[((size_t)blockIdx.y*3 + 2)*HW + i] = a2;
}

__global__ void cyc_combine_kernel(const float* __restrict__ part, const float* __restrict__ csuminv,
                                   float* __restrict__ cyc, int b) {
    int i = blockIdx.x * 256 + threadIdx.x;
    int c = blockIdx.y;
    float s = 0.f;
    for (int k = 0; k < 32; ++k) s += part[((size_t)k*3 + c)*HW + i];
    cyc[((size_t)b*3 + c)*HW + i] = s * csuminv[i];
}

__global__ void flow_kernel(const float* __restrict__ coords, float* __restrict__ out) {
    size_t idx = (size_t)blockIdx.x * 256 + threadIdx.x;
    int x4 = (int)(idx & 255);
    int y4 = (int)((idx >> 8) & 255);
    int ch = (int)((idx >> 16) & 1);
    int b  = (int)(idx >> 17);
    int w = x4 >> 2, h = y4 >> 2;
    int m = h*64 + w;
    float c1 = coords[((size_t)b*2 + ch)*HW + m];
    float c0 = (ch == 0) ? (float)w : (float)h;
    out[OUT_FLOW + idx] = c1 - c0;
}

__global__ void imgout_kernel(const float* __restrict__ attn, const float* __restrict__ cyc,
                              float* __restrict__ out) {
    size_t idx = (size_t)blockIdx.x * 256 + threadIdx.x;
    int x4 = (int)(idx & 255);
    int y4 = (int)((idx >> 8) & 255);
    int rest = (int)(idx >> 16);
    int ch = rest % 3, b = rest / 3;
    int m = (y4 >> 2)*64 + (x4 >> 2);
    out[OUT_IMG  + idx] = attn[((size_t)b*HW + m)*3 + ch];
    out[OUT_CYCO + idx] = cyc[((size_t)b*3 + ch)*HW + m];
}

__global__ void loss_partial_kernel(const float* __restrict__ xf, const float* __restrict__ yf,
                                    const float* __restrict__ means, const float* __restrict__ rnorms,
                                    float* __restrict__ part) {
    __shared__ float red[256];
    size_t base = (size_t)blockIdx.x * 4096;
    float s = 0.f;
    for (int k = 0; k < 16; ++k) {
        size_t id = base + (size_t)k*256 + threadIdx.x;
        int m  = (int)(id & (HW - 1));
        int bc = (int)(id >> 12);
        int b  = bc >> 8;
        float th = (xf[id] - means[bc])          * rnorms[(size_t)b*HW + m];
        float ph = (yf[id] - means[NB*NCH + bc]) * rnorms[(size_t)(NB + b)*HW + m];
        s += fabsf(th - ph);
    }
    red[threadIdx.x] = s; __syncthreads();
    for (int st = 128; st > 0; st >>= 1) {
        if (threadIdx.x < st) red[threadIdx.x] += red[threadIdx.x + st];
        __syncthreads();
    }
    if (threadIdx.x == 0) part[blockIdx.x] = red[0];
}

__global__ void loss_final_kernel(const float* __restrict__ part, float* __restrict__ out) {
    __shared__ float red[256];
    float s = 0.f;
    for (int k = threadIdx.x; k < 1024; k += 256) s += part[k];
    red[threadIdx.x] = s; __syncthreads();
    for (int st = 128; st > 0; st >>= 1) {
        if (threadIdx.x < st) red[threadIdx.x] += red[threadIdx.x + st];
        __syncthreads();
    }
    if (threadIdx.x == 0) out[OUT_LOSS] = red[0] * (1.0f / 4194304.0f);
}

extern "C" void kernel_launch(void* const* d_in, const int* in_sizes, int n_in,
                              void* d_out, int out_size, void* d_ws, size_t ws_size,
                              hipStream_t stream) {
    (void)in_sizes; (void)n_in; (void)out_size; (void)ws_size;
    const float* xf   = (const float*)d_in[0];
    const float* yf   = (const float*)d_in[1];
    const float* yimg = (const float*)d_in[2];
    float* out = (float*)d_out;
    float* ws  = (float*)d_ws;

    _Float16* yf16 = (_Float16*)(ws + OFF_YT);
    float* yi      = ws + OFF_YI;
    float* means   = ws + OFF_MEAN;
    float* rnorms  = ws + OFF_RNORM;
    float* nsqp    = ws + OFF_NSQP;
    float* fbuf    = ws + OFF_F;
    float* yp      = ws + OFF_YP;
    float* rowp    = ws + OFF_ROWP;
    float* colp    = ws + OFF_COLP;
    float* rmax    = ws + OFF_RMAX;
    float* rsuminv = ws + OFF_RSUM;
    float* cmax    = ws + OFF_CMAX;
    float* csuminv = ws + OFF_CSUM;
    float* coords  = ws + OFF_COORD;
    float* attn    = ws + OFF_ATTN;
    float* cyc     = ws + OFF_CYC;
    float* cycp    = ws + OFF_CYCP;
    float* lossp   = ws + OFF_LOSSP;
    _Float16* th = (_Float16*)(ws + OFF_F16);
    _Float16* tl = th + (size_t)HW*NCH;
    _Float16* ph = tl + (size_t)HW*NCH;
    _Float16* pl = ph + (size_t)HW*NCH;

    mean_kernel        <<<dim3(NB*NCH, 2),   256, 0, stream>>>(xf, yf, means);
    nsq_partial_kernel <<<dim3(16, 8, 8),    256, 0, stream>>>(xf, yf, means, nsqp);
    nsq_combine_kernel <<<dim3(16, 8),       256, 0, stream>>>(nsqp, rnorms);
    ycast_kernel       <<<2048,              256, 0, stream>>>(yf, yf16);
    avgpool_kernel     <<<NB*3*HW/256,       256, 0, stream>>>(yimg, yi);

    for (int b = 0; b < NB; ++b) {
        prep_kernel        <<<dim3(8, 128, 2), 256, 0, stream>>>(xf, yf, means, th, tl, ph, pl, b);
        gemm_f_kernel      <<<dim3(32, 32),    256, 0, stream>>>(th, tl, ph, pl, rnorms, yi,
                                                                 fbuf, rowp, colp, b);
        row_combine_kernel <<<16,              256, 0, stream>>>(rowp, rmax, rsuminv, coords, attn, b);
        col_combine_kernel <<<16,              256, 0, stream>>>(colp, cmax, csuminv);
        gemm_y_kernel      <<<dim3(32, 8),     512, 0, stream>>>(fbuf, rmax, yf16, yp, b);
        ycombine_kernel    <<<NCH*HW/256,      256, 0, stream>>>(yp, rsuminv, out, b);
        cyc_partial_kernel <<<dim3(16, 32),    256, 0, stream>>>(fbuf, cmax, attn, cycp, b);
        cyc_combine_kernel <<<dim3(16, 3),     256, 0, stream>>>(cycp, csuminv, cyc, b);
    }

    flow_kernel        <<<NB*2*65536/256, 256, 0, stream>>>(coords, out);
    imgout_kernel      <<<NB*3*65536/256, 256, 0, stream>>>(attn, cyc, out);
    loss_partial_kernel<<<1024,           256, 0, stream>>>(xf, yf, means, rnorms, lossp);
    loss_final_kernel  <<<1,              256, 0, stream>>>(lossp, out);
}

// Round 6
// 539.989 us; speedup vs baseline: 5.4043x; 1.0223x over previous
//
#include <hip/hip_runtime.h>
#include <math.h>

#define HW   4096
#define NCH  256
#define NB   4

constexpr float TEMP  = (float)(0.0001 * 5.0);
constexpr float INV_T = 1.0f / TEMP;
constexpr float EPSN  = 2.220446049250313e-16f;

typedef __attribute__((ext_vector_type(8))) _Float16 f16x8;
typedef __attribute__((ext_vector_type(4))) float    f32x4;

// ---------------- workspace layout (in floats) ----------------
constexpr size_t OFF_YT    = 0;                                 // yf16: NB*HW*NCH f16
constexpr size_t OFF_YI    = OFF_YT    + (size_t)NB*HW*NCH;     // NB*3*HW
constexpr size_t OFF_MEAN  = OFF_YI    + (size_t)NB*3*HW;       // 2*NB*NCH
constexpr size_t OFF_RNORM = OFF_MEAN  + (size_t)2*NB*NCH;      // 2*NB*HW
constexpr size_t OFF_NSQP  = OFF_RNORM + (size_t)2*NB*HW;       // 2*NB*8*HW
constexpr size_t OFF_F     = OFF_NSQP  + (size_t)2*NB*8*HW;     // HW*HW
constexpr size_t OFF_YP    = OFF_F     + (size_t)HW*HW;         // 8*NCH*HW (split-K partials)
// rowp/colp ALIAS the yp buffer: consumed by row/col combine before gemm_y writes yp
constexpr size_t OFF_ROWP  = OFF_YP;                            // [32 ntile][7][HW]
constexpr size_t OFF_COLP  = OFF_YP + (size_t)32*7*HW;          // [32 mtile][2][HW]
constexpr size_t OFF_RMAX  = OFF_YP    + (size_t)8*NCH*HW;
constexpr size_t OFF_RSUM  = OFF_RMAX  + HW;
constexpr size_t OFF_CMAX  = OFF_RSUM  + HW;
constexpr size_t OFF_CSUM  = OFF_CMAX  + HW;
constexpr size_t OFF_COORD = OFF_CSUM  + HW;                // NB*2*HW
constexpr size_t OFF_ATTN  = OFF_COORD + (size_t)NB*2*HW;   // NB*HW*3
constexpr size_t OFF_CYC   = OFF_ATTN  + (size_t)NB*HW*3;   // NB*3*HW
constexpr size_t OFF_CYCP  = OFF_CYC   + (size_t)NB*3*HW;   // 32*3*HW
constexpr size_t OFF_LOSSP = OFF_CYCP  + (size_t)32*3*HW;   // 1024
constexpr size_t OFF_F16   = OFF_LOSSP + 1024;              // 4 * 524288 floats

// ---------------- output layout (floats) ----------------
constexpr size_t OUT_Y    = 0;
constexpr size_t OUT_FLOW = (size_t)NB*NCH*HW;
constexpr size_t OUT_IMG  = OUT_FLOW + (size_t)NB*2*256*256;
constexpr size_t OUT_CYCO = OUT_IMG  + (size_t)NB*3*256*256;
constexpr size_t OUT_LOSS = OUT_CYCO + (size_t)NB*3*256*256;

__device__ __forceinline__ void gload16(const void* g, void* l) {
    __builtin_amdgcn_global_load_lds(
        (const __attribute__((address_space(1))) unsigned int*)g,
        (__attribute__((address_space(3))) unsigned int*)l, 16, 0, 0);
}

__global__ void mean_kernel(const float* __restrict__ xf, const float* __restrict__ yf,
                            float* __restrict__ means) {
    const float* src = (blockIdx.y == 0 ? xf : yf) + (size_t)blockIdx.x * HW;
    float s = 0.f;
    for (int i = threadIdx.x; i < HW; i += 256) s += src[i];
    __shared__ float red[256];
    red[threadIdx.x] = s; __syncthreads();
    for (int st = 128; st > 0; st >>= 1) {
        if (threadIdx.x < st) red[threadIdx.x] += red[threadIdx.x + st];
        __syncthreads();
    }
    if (threadIdx.x == 0) means[blockIdx.y * (NB*NCH) + blockIdx.x] = red[0] * (1.0f / HW);
}

__global__ void nsq_partial_kernel(const float* __restrict__ xf, const float* __restrict__ yf,
                                   const float* __restrict__ means, float* __restrict__ part) {
    int t = blockIdx.z >> 2, b = blockIdx.z & 3;
    int m = blockIdx.x * 256 + threadIdx.x;
    int c0 = blockIdx.y * 32;
    const float* src = (t == 0 ? xf : yf) + (size_t)b * NCH * HW;
    const float* mn = means + t * (NB*NCH) + b * NCH;
    float acc = 0.f;
    for (int c = c0; c < c0 + 32; ++c) {
        float v = src[(size_t)c * HW + m] - mn[c];
        acc += v * v;
    }
    part[(((size_t)t*NB + b) * 8 + blockIdx.y) * HW + m] = acc;
}

__global__ void nsq_combine_kernel(const float* __restrict__ part, float* __restrict__ rnorms) {
    int t = blockIdx.y >> 2, b = blockIdx.y & 3;
    int m = blockIdx.x * 256 + threadIdx.x;
    const float* p = part + ((size_t)t*NB + b) * 8 * HW + m;
    float s = 0.f;
    for (int k = 0; k < 8; ++k) s += p[(size_t)k * HW];
    rnorms[((size_t)t*NB + b) * HW + m] = 1.0f / (sqrtf(s) + EPSN);
}

__global__ void ycast_kernel(const float* __restrict__ yf, _Float16* __restrict__ yf16) {
    size_t i = ((size_t)blockIdx.x * 256 + threadIdx.x) * 8;
    const float4* s = (const float4*)(yf + i);
    float4 v0 = s[0], v1 = s[1];
    f16x8 o;
    o[0]=(_Float16)v0.x; o[1]=(_Float16)v0.y; o[2]=(_Float16)v0.z; o[3]=(_Float16)v0.w;
    o[4]=(_Float16)v1.x; o[5]=(_Float16)v1.y; o[6]=(_Float16)v1.z; o[7]=(_Float16)v1.w;
    *(f16x8*)(yf16 + i) = o;
}

__global__ void prep_kernel(const float* __restrict__ xf, const float* __restrict__ yf,
                            const float* __restrict__ means,
                            _Float16* __restrict__ th, _Float16* __restrict__ tl,
                            _Float16* __restrict__ ph, _Float16* __restrict__ pl, int b) {
    __shared__ float tile[32][33];
    int t = blockIdx.z;
    int c0 = blockIdx.x * 32, m0 = blockIdx.y * 32;
    const float* src = (t == 0 ? xf : yf) + (size_t)b * NCH * HW;
    const float* mn  = means + t * (NB*NCH) + b * NCH;
    int tx = threadIdx.x & 31, ty = threadIdx.x >> 5;
    for (int i = ty; i < 32; i += 8)
        tile[i][tx] = src[(size_t)(c0 + i) * HW + m0 + tx] - mn[c0 + i];
    __syncthreads();
    _Float16* H = (t == 0 ? th : ph);
    _Float16* L = (t == 0 ? tl : pl);
    for (int i = ty; i < 32; i += 8) {
        float v = tile[tx][i];
        _Float16 h = (_Float16)v;
        _Float16 l = (_Float16)(v - (float)h);
        H[(size_t)(m0 + i)*NCH + c0 + tx] = h;
        L[(size_t)(m0 + i)*NCH + c0 + tx] = l;
    }
}

__global__ void avgpool_kernel(const float* __restrict__ yimg, float* __restrict__ yi) {
    size_t idx = (size_t)blockIdx.x * 256 + threadIdx.x;
    int m  = (int)(idx & (HW - 1));
    int bc = (int)(idx >> 12);
    int h = m >> 6, w = m & 63;
    const float* p = yimg + (size_t)bc * 65536 + (size_t)(h*4) * 256 + w*4;
    float s = 0.f;
    #pragma unroll
    for (int dy = 0; dy < 4; ++dy) {
        #pragma unroll
        for (int dx = 0; dx < 4; ++dx) s += p[dy*256 + dx];
    }
    yi[idx] = s * (1.0f/16.0f);
}

// f^T accumulator GEMM: A = phi (n rows), B = theta (m rows) ->
// acc[i][j]: col(lane&15)=m, row(regs)=n. float4 f-writes + cheap reductions.
__global__ __launch_bounds__(256) void gemm_f_kernel(
        const _Float16* __restrict__ th, const _Float16* __restrict__ tl,
        const _Float16* __restrict__ ph, const _Float16* __restrict__ pl,
        const float* __restrict__ rnorms, const float* __restrict__ yi,
        float* __restrict__ f, float* __restrict__ rowp, float* __restrict__ colp,
        int b) {
    __shared__ char lds[4][8192];   // [0]=A hi (phi), [1]=A lo, [2]=B hi (theta), [3]=B lo
    int tid  = threadIdx.x;
    int lane = tid & 63;
    int w = tid >> 6, wm = w >> 1, wn = w & 1;   // wm: n-block, wn: m-block
    int m0 = blockIdx.y * 128, n0 = blockIdx.x * 128;  // m0: f rows, n0: f cols

    int o0 = tid * 16, o1 = o0 + 4096;
    int r0 = o0 >> 6, s0 = (o0 >> 4) & 3, g0 = s0 ^ ((r0 >> 1) & 3);
    int r1 = o1 >> 6, s1 = (o1 >> 4) & 3, g1 = s1 ^ ((r1 >> 1) & 3);
    size_t ga0 = (size_t)(n0 + r0)*NCH + g0*8;   // A rows = phi rows (n)
    size_t ga1 = (size_t)(n0 + r1)*NCH + g1*8;
    size_t gb0 = (size_t)(m0 + r0)*NCH + g0*8;   // B rows = theta rows (m)
    size_t gb1 = (size_t)(m0 + r1)*NCH + g1*8;

    int fra = wm*64 + (lane & 15);   // A fragment rows (n-local)
    int frb = wn*64 + (lane & 15);   // B fragment rows (m-local)
    int ks  = lane >> 4;

    f32x4 acc[4][4];
    #pragma unroll
    for (int i = 0; i < 4; ++i)
        #pragma unroll
        for (int j = 0; j < 4; ++j) acc[i][j] = (f32x4){0.f, 0.f, 0.f, 0.f};

    for (int kt = 0; kt < 8; ++kt) {
        int k0 = kt * 32;
        gload16(ph + ga0 + k0, &lds[0][o0]);
        gload16(ph + ga1 + k0, &lds[0][o1]);
        gload16(pl + ga0 + k0, &lds[1][o0]);
        gload16(pl + ga1 + k0, &lds[1][o1]);
        gload16(th + gb0 + k0, &lds[2][o0]);
        gload16(th + gb1 + k0, &lds[2][o1]);
        gload16(tl + gb0 + k0, &lds[3][o0]);
        gload16(tl + gb1 + k0, &lds[3][o1]);
        __syncthreads();

        f16x8 ah[4], al[4], bh[4], bl[4];
        #pragma unroll
        for (int i = 0; i < 4; ++i) {
            int rowa = fra + i*16;
            int offa = rowa*64 + ((ks ^ ((rowa >> 1) & 3)) << 4);
            ah[i] = *(const f16x8*)&lds[0][offa];
            al[i] = *(const f16x8*)&lds[1][offa];
            int rowb = frb + i*16;
            int offb = rowb*64 + ((ks ^ ((rowb >> 1) & 3)) << 4);
            bh[i] = *(const f16x8*)&lds[2][offb];
            bl[i] = *(const f16x8*)&lds[3][offb];
        }
        #pragma unroll
        for (int i = 0; i < 4; ++i)
            #pragma unroll
            for (int j = 0; j < 4; ++j) {
                acc[i][j] = __builtin_amdgcn_mfma_f32_16x16x32_f16(ah[i], bh[j], acc[i][j], 0, 0, 0);
                acc[i][j] = __builtin_amdgcn_mfma_f32_16x16x32_f16(ah[i], bl[j], acc[i][j], 0, 0, 0);
                acc[i][j] = __builtin_amdgcn_mfma_f32_16x16x32_f16(al[i], bh[j], acc[i][j], 0, 0, 0);
            }
        __syncthreads();
    }

    // ---- scale in place: f[m][n] = accT * rnx[m] * rny[n] ----
    const float* rnx = rnorms + (size_t)b * HW;        // f-row (theta/m) norms
    const float* rny = rnorms + (size_t)(NB + b) * HW; // f-col (phi/n) norms
    int mg[4];  float rxv[4];
    #pragma unroll
    for (int j = 0; j < 4; ++j) {
        mg[j] = m0 + wn*64 + j*16 + (lane & 15);
        rxv[j] = rnx[mg[j]];
    }
    int nl0 = wm*64 + (lane >> 4)*4;   // n-local base (i=0, r=0)
    #pragma unroll
    for (int i = 0; i < 4; ++i)
        #pragma unroll
        for (int r = 0; r < 4; ++r) {
            float ry = rny[n0 + nl0 + i*16 + r];
            #pragma unroll
            for (int j = 0; j < 4; ++j) acc[i][j][r] *= rxv[j] * ry;
        }

    // ---- write f: one float4 per (i,j) ----
    #pragma unroll
    for (int j = 0; j < 4; ++j)
        #pragma unroll
        for (int i = 0; i < 4; ++i)
            *(f32x4*)&f[(size_t)mg[j]*HW + n0 + nl0 + i*16] = acc[i][j];

    // ---- stats (deterministic; LDS reuse after final loop barrier) ----
    float* S     = (float*)&lds[0][0];
    float* rowm  = S;          // [2 wm][128 m]
    float* sums6 = S + 256;    // [2 wm][128 m][6]
    float* colm  = S + 1792;   // [2 wn][128 n]
    float* colsm = S + 2048;   // [2 wn][128 n]

    // phase A: per-wave maxes
    #pragma unroll
    for (int j = 0; j < 4; ++j) {
        float v = acc[0][j][0];
        #pragma unroll
        for (int i = 0; i < 4; ++i)
            #pragma unroll
            for (int r = 0; r < 4; ++r) v = fmaxf(v, acc[i][j][r]);
        v = fmaxf(v, __shfl_xor(v, 16));
        v = fmaxf(v, __shfl_xor(v, 32));
        if ((lane >> 4) == 0) rowm[wm*128 + wn*64 + j*16 + lane] = v;
    }
    #pragma unroll
    for (int i = 0; i < 4; ++i)
        #pragma unroll
        for (int r = 0; r < 4; ++r) {
            float v = fmaxf(fmaxf(acc[i][0][r], acc[i][1][r]),
                            fmaxf(acc[i][2][r], acc[i][3][r]));
            #pragma unroll
            for (int d = 1; d < 16; d <<= 1) v = fmaxf(v, __shfl_xor(v, d));
            if ((lane & 15) == 0) colm[wn*128 + wm*64 + i*16 + (lane >> 4)*4 + r] = v;
        }
    __syncthreads();

    // phase B: exp sums vs block maxes
    float bm[4];
    #pragma unroll
    for (int j = 0; j < 4; ++j) {
        int ml = wn*64 + j*16 + (lane & 15);
        bm[j] = fmaxf(rowm[ml], rowm[128 + ml]);
    }
    float a6[4][6];
    #pragma unroll
    for (int j = 0; j < 4; ++j)
        #pragma unroll
        for (int q = 0; q < 6; ++q) a6[j][q] = 0.f;
    const float* yib = yi + (size_t)b * 3 * HW;
    #pragma unroll
    for (int i = 0; i < 4; ++i)
        #pragma unroll
        for (int r = 0; r < 4; ++r) {
            int ng = n0 + nl0 + i*16 + r;
            float xc = (float)(ng & 63), yc = (float)(ng >> 6);
            float y0 = yib[ng], y1 = yib[HW + ng], y2 = yib[2*HW + ng];
            #pragma unroll
            for (int j = 0; j < 4; ++j) {
                float e = __expf((acc[i][j][r] - bm[j]) * INV_T);
                a6[j][0] += e;      a6[j][1] += e*xc; a6[j][2] += e*yc;
                a6[j][3] += e*y0;   a6[j][4] += e*y1; a6[j][5] += e*y2;
            }
        }
    #pragma unroll
    for (int j = 0; j < 4; ++j)
        #pragma unroll
        for (int q = 0; q < 6; ++q) {
            float v = a6[j][q];
            v += __shfl_xor(v, 16);
            v += __shfl_xor(v, 32);
            if ((lane >> 4) == 0) sums6[(wm*128 + wn*64 + j*16 + lane)*6 + q] = v;
        }
    #pragma unroll
    for (int i = 0; i < 4; ++i)
        #pragma unroll
        for (int r = 0; r < 4; ++r) {
            int nl = wm*64 + i*16 + (lane >> 4)*4 + r;
            float cm = fmaxf(colm[nl], colm[128 + nl]);
            float cs = 0.f;
            #pragma unroll
            for (int j = 0; j < 4; ++j) cs += __expf((acc[i][j][r] - cm) * INV_T);
            #pragma unroll
            for (int d = 1; d < 16; d <<= 1) cs += __shfl_xor(cs, d);
            if ((lane & 15) == 0) colsm[wn*128 + nl] = cs;
        }
    __syncthreads();

    // phase C: global partial writes
    if (tid < 128) {
        int ml = tid;
        float m2 = fmaxf(rowm[ml], rowm[128 + ml]);
        rowp[((size_t)blockIdx.x*7 + 0)*HW + m0 + ml] = m2;
        #pragma unroll
        for (int q = 0; q < 6; ++q)
            rowp[((size_t)blockIdx.x*7 + 1 + q)*HW + m0 + ml] =
                sums6[ml*6 + q] + sums6[(128 + ml)*6 + q];
    } else {
        int nl = tid - 128;
        float c2 = fmaxf(colm[nl], colm[128 + nl]);
        colp[((size_t)blockIdx.y*2 + 0)*HW + n0 + nl] = c2;
        colp[((size_t)blockIdx.y*2 + 1)*HW + n0 + nl] = colsm[nl] + colsm[128 + nl];
    }
}

// combine 32 n-tile row partials -> rmax, rsuminv, coords, attn
__global__ void row_combine_kernel(const float* __restrict__ rowp,
        float* __restrict__ rmax, float* __restrict__ rsuminv,
        float* __restrict__ coords, float* __restrict__ attn, int b) {
    int m = blockIdx.x * 256 + threadIdx.x;
    float gm = -3.0e38f;
    for (int t = 0; t < 32; ++t) gm = fmaxf(gm, rowp[((size_t)t*7)*HW + m]);
    float S=0, CX=0, CY=0, A0=0, A1=0, A2=0;
    for (int t = 0; t < 32; ++t) {
        const float* p = rowp + (size_t)t*7*HW + m;
        float wgt = __expf((p[0] - gm) * INV_T);
        S  += p[1*HW] * wgt; CX += p[2*HW] * wgt; CY += p[3*HW] * wgt;
        A0 += p[4*HW] * wgt; A1 += p[5*HW] * wgt; A2 += p[6*HW] * wgt;
    }
    float inv = 1.0f / S;
    rmax[m] = gm; rsuminv[m] = inv;
    coords[((size_t)b*2 + 0)*HW + m] = CX * inv;
    coords[((size_t)b*2 + 1)*HW + m] = CY * inv;
    attn[((size_t)b*HW + m)*3 + 0] = A0 * inv;
    attn[((size_t)b*HW + m)*3 + 1] = A1 * inv;
    attn[((size_t)b*HW + m)*3 + 2] = A2 * inv;
}

// combine 32 m-tile col partials -> cmax, csuminv
__global__ void col_combine_kernel(const float* __restrict__ colp,
        float* __restrict__ cmax, float* __restrict__ csuminv) {
    int n = blockIdx.x * 256 + threadIdx.x;
    float gm = -3.0e38f;
    for (int t = 0; t < 32; ++t) gm = fmaxf(gm, colp[((size_t)t*2)*HW + n]);
    float S = 0.f;
    for (int t = 0; t < 32; ++t) {
        const float* p = colp + (size_t)t*2*HW + n;
        S += p[1*HW] * __expf((p[0] - gm) * INV_T);
    }
    cmax[n] = gm;
    csuminv[n] = 1.0f / S;
}

// y partials: MFMA f16. P recomputed from f on the fly (A), yf16 as B.
__global__ __launch_bounds__(512) void gemm_y_kernel(const float* __restrict__ f,
        const float* __restrict__ rmax, const _Float16* __restrict__ yf16,
        float* __restrict__ yp, int b) {
    __shared__ __align__(16) char ldsA[8192];
    __shared__ __align__(16) char ldsB[16384];
    int tid  = threadIdx.x;
    int lane = tid & 63;
    int w = tid >> 6, wm = w >> 2, wn = w & 3;
    int m0 = blockIdx.x * 128;
    int ks = blockIdx.y;
    const _Float16* Yb = yf16 + (size_t)b * NCH * HW;

    int ar = tid >> 2, akc = tid & 3;
    int aoff = ar*64 + ((akc ^ ((ar >> 1) & 3)) << 4);
    float arm = rmax[m0 + ar];
    const float* frow = f + (size_t)(m0 + ar)*HW + akc*8;

    int o0 = tid*16, o1 = o0 + 8192;
    int br0 = o0 >> 6, bs0 = (o0 >> 4) & 3, bg0 = bs0 ^ ((br0 >> 1) & 3);
    int br1 = o1 >> 6, bs1 = (o1 >> 4) & 3, bg1 = bs1 ^ ((br1 >> 1) & 3);
    size_t gb0 = (size_t)br0*HW + bg0*8;
    size_t gb1 = (size_t)br1*HW + bg1*8;

    int fra = wm*64 + (lane & 15);
    int frb = wn*64 + (lane & 15);
    int kslot = lane >> 4;

    f32x4 acc[4][4];
    #pragma unroll
    for (int i = 0; i < 4; ++i)
        #pragma unroll
        for (int j = 0; j < 4; ++j) acc[i][j] = (f32x4){0.f, 0.f, 0.f, 0.f};

    for (int k0 = ks*512; k0 < ks*512 + 512; k0 += 32) {
        gload16(Yb + gb0 + k0, &ldsB[o0]);
        gload16(Yb + gb1 + k0, &ldsB[o1]);
        const float4* fp = (const float4*)(frow + k0);
        float4 v0 = fp[0], v1 = fp[1];
        f16x8 pk;
        pk[0] = (_Float16)__expf((v0.x - arm) * INV_T);
        pk[1] = (_Float16)__expf((v0.y - arm) * INV_T);
        pk[2] = (_Float16)__expf((v0.z - arm) * INV_T);
        pk[3] = (_Float16)__expf((v0.w - arm) * INV_T);
        pk[4] = (_Float16)__expf((v1.x - arm) * INV_T);
        pk[5] = (_Float16)__expf((v1.y - arm) * INV_T);
        pk[6] = (_Float16)__expf((v1.z - arm) * INV_T);
        pk[7] = (_Float16)__expf((v1.w - arm) * INV_T);
        *(f16x8*)&ldsA[aoff] = pk;
        __syncthreads();

        f16x8 af[4], bf[4];
        #pragma unroll
        for (int i = 0; i < 4; ++i) {
            int rowa = fra + i*16;
            af[i] = *(const f16x8*)&ldsA[rowa*64 + ((kslot ^ ((rowa >> 1) & 3)) << 4)];
            int rowb = frb + i*16;
            bf[i] = *(const f16x8*)&ldsB[rowb*64 + ((kslot ^ ((rowb >> 1) & 3)) << 4)];
        }
        #pragma unroll
        for (int i = 0; i < 4; ++i)
            #pragma unroll
            for (int j = 0; j < 4; ++j)
                acc[i][j] = __builtin_amdgcn_mfma_f32_16x16x32_f16(af[i], bf[j], acc[i][j], 0, 0, 0);
        __syncthreads();
    }

    #pragma unroll
    for (int i = 0; i < 4; ++i) {
        int m = m0 + wm*64 + i*16 + (lane >> 4) * 4;
        #pragma unroll
        for (int j = 0; j < 4; ++j) {
            int c = wn*64 + j*16 + (lane & 15);
            *(f32x4*)(yp + ((size_t)ks*NCH + c)*HW + m) = acc[i][j];
        }
    }
}

__global__ void ycombine_kernel(const float* __restrict__ yp, const float* __restrict__ rsuminv,
                                float* __restrict__ out, int b) {
    size_t idx = (size_t)blockIdx.x * 256 + threadIdx.x;
    int m = (int)(idx & (HW - 1));
    float s = 0.f;
    #pragma unroll
    for (int k = 0; k < 8; ++k) s += yp[(size_t)k*NCH*HW + idx];
    out[OUT_Y + (size_t)b*NCH*HW + idx] = s * rsuminv[m];
}

// cyc partial over row-chunks of 128 (512 blocks)
__global__ __launch_bounds__(256) void cyc_partial_kernel(const float* __restrict__ f,
        const float* __restrict__ cmax, const float* __restrict__ attn,
        float* __restrict__ part, int b) {
    __shared__ float at[128*3];
    int i  = blockIdx.x * 256 + threadIdx.x;
    int j0 = blockIdx.y * 128;
    for (int k = threadIdx.x; k < 384; k += 256)
        at[k] = attn[((size_t)b*HW + j0)*3 + k];
    __syncthreads();
    float cm = cmax[i];
    float a0=0, a1=0, a2=0;
    for (int jj = 0; jj < 128; ++jj) {
        float e = __expf((f[(size_t)(j0+jj)*HW + i] - cm) * INV_T);
        a0 = fmaf(e, at[jj*3+0], a0);
        a1 = fmaf(e, at[jj*3+1], a1);
        a2 = fmaf(e, at[jj*3+2], a2);
    }
    part[((size_t)blockIdx.y*3 + 0)*HW + i] = a0;
    part[((size_t)blockIdx.y*3 + 1)*HW + i] = a1;
    part[((size_t)blockIdx.y*3 + 2)*HW + i] = a2;
}

__global__ void cyc_combine_kernel(const float* __restrict__ part, const float* __restrict__ csuminv,
                                   float* __restrict__ cyc, int b) {
    int i = blockIdx.x * 256 + threadIdx.x;
    int c = blockIdx.y;
    float s = 0.f;
    for (int k = 0; k < 32; ++k) s += part[((size_t)k*3 + c)*HW + i];
    cyc[((size_t)b*3 + c)*HW + i] = s * csuminv[i];
}

__global__ void flow_kernel(const float* __restrict__ coords, float* __restrict__ out) {
    size_t idx = (size_t)blockIdx.x * 256 + threadIdx.x;
    int x4 = (int)(idx & 255);
    int y4 = (int)((idx >> 8) & 255);
    int ch = (int)((idx >> 16) & 1);
    int b  = (int)(idx >> 17);
    int w = x4 >> 2, h = y4 >> 2;
    int m = h*64 + w;
    float c1 = coords[((size_t)b*2 + ch)*HW + m];
    float c0 = (ch == 0) ? (float)w : (float)h;
    out[OUT_FLOW + idx] = c1 - c0;
}

__global__ void imgout_kernel(const float* __restrict__ attn, const float* __restrict__ cyc,
                              float* __restrict__ out) {
    size_t idx = (size_t)blockIdx.x * 256 + threadIdx.x;
    int x4 = (int)(idx & 255);
    int y4 = (int)((idx >> 8) & 255);
    int rest = (int)(idx >> 16);
    int ch = rest % 3, b = rest / 3;
    int m = (y4 >> 2)*64 + (x4 >> 2);
    out[OUT_IMG  + idx] = attn[((size_t)b*HW + m)*3 + ch];
    out[OUT_CYCO + idx] = cyc[((size_t)b*3 + ch)*HW + m];
}

__global__ void loss_partial_kernel(const float* __restrict__ xf, const float* __restrict__ yf,
                                    const float* __restrict__ means, const float* __restrict__ rnorms,
                                    float* __restrict__ part) {
    __shared__ float red[256];
    size_t base = (size_t)blockIdx.x * 4096;
    float s = 0.f;
    for (int k = 0; k < 16; ++k) {
        size_t id = base + (size_t)k*256 + threadIdx.x;
        int m  = (int)(id & (HW - 1));
        int bc = (int)(id >> 12);
        int b  = bc >> 8;
        float th = (xf[id] - means[bc])          * rnorms[(size_t)b*HW + m];
        float ph = (yf[id] - means[NB*NCH + bc]) * rnorms[(size_t)(NB + b)*HW + m];
        s += fabsf(th - ph);
    }
    red[threadIdx.x] = s; __syncthreads();
    for (int st = 128; st > 0; st >>= 1) {
        if (threadIdx.x < st) red[threadIdx.x] += red[threadIdx.x + st];
        __syncthreads();
    }
    if (threadIdx.x == 0) part[blockIdx.x] = red[0];
}

__global__ void loss_final_kernel(const float* __restrict__ part, float* __restrict__ out) {
    __shared__ float red[256];
    float s = 0.f;
    for (int k = threadIdx.x; k < 1024; k += 256) s += part[k];
    red[threadIdx.x] = s; __syncthreads();
    for (int st = 128; st > 0; st >>= 1) {
        if (threadIdx.x < st) red[threadIdx.x] += red[threadIdx.x + st];
        __syncthreads();
    }
    if (threadIdx.x == 0) out[OUT_LOSS] = red[0] * (1.0f / 4194304.0f);
}

extern "C" void kernel_launch(void* const* d_in, const int* in_sizes, int n_in,
                              void* d_out, int out_size, void* d_ws, size_t ws_size,
                              hipStream_t stream) {
    (void)in_sizes; (void)n_in; (void)out_size; (void)ws_size;
    const float* xf   = (const float*)d_in[0];
    const float* yf   = (const float*)d_in[1];
    const float* yimg = (const float*)d_in[2];
    float* out = (float*)d_out;
    float* ws  = (float*)d_ws;

    _Float16* yf16 = (_Float16*)(ws + OFF_YT);
    float* yi      = ws + OFF_YI;
    float* means   = ws + OFF_MEAN;
    float* rnorms  = ws + OFF_RNORM;
    float* nsqp    = ws + OFF_NSQP;
    float* fbuf    = ws + OFF_F;
    float* yp      = ws + OFF_YP;
    float* rowp    = ws + OFF_ROWP;
    float* colp    = ws + OFF_COLP;
    float* rmax    = ws + OFF_RMAX;
    float* rsuminv = ws + OFF_RSUM;
    float* cmax    = ws + OFF_CMAX;
    float* csuminv = ws + OFF_CSUM;
    float* coords  = ws + OFF_COORD;
    float* attn    = ws + OFF_ATTN;
    float* cyc     = ws + OFF_CYC;
    float* cycp    = ws + OFF_CYCP;
    float* lossp   = ws + OFF_LOSSP;
    _Float16* th = (_Float16*)(ws + OFF_F16);
    _Float16* tl = th + (size_t)HW*NCH;
    _Float16* ph = tl + (size_t)HW*NCH;
    _Float16* pl = ph + (size_t)HW*NCH;

    mean_kernel        <<<dim3(NB*NCH, 2),   256, 0, stream>>>(xf, yf, means);
    nsq_partial_kernel <<<dim3(16, 8, 8),    256, 0, stream>>>(xf, yf, means, nsqp);
    nsq_combine_kernel <<<dim3(16, 8),       256, 0, stream>>>(nsqp, rnorms);
    ycast_kernel       <<<2048,              256, 0, stream>>>(yf, yf16);
    avgpool_kernel     <<<NB*3*HW/256,       256, 0, stream>>>(yimg, yi);

    for (int b = 0; b < NB; ++b) {
        prep_kernel        <<<dim3(8, 128, 2), 256, 0, stream>>>(xf, yf, means, th, tl, ph, pl, b);
        gemm_f_kernel      <<<dim3(32, 32),    256, 0, stream>>>(th, tl, ph, pl, rnorms, yi,
                                                                 fbuf, rowp, colp, b);
        row_combine_kernel <<<16,              256, 0, stream>>>(rowp, rmax, rsuminv, coords, attn, b);
        col_combine_kernel <<<16,              256, 0, stream>>>(colp, cmax, csuminv);
        gemm_y_kernel      <<<dim3(32, 8),     512, 0, stream>>>(fbuf, rmax, yf16, yp, b);
        ycombine_kernel    <<<NCH*HW/256,      256, 0, stream>>>(yp, rsuminv, out, b);
        cyc_partial_kernel <<<dim3(16, 32),    256, 0, stream>>>(fbuf, cmax, attn, cycp, b);
        cyc_combine_kernel <<<dim3(16, 3),     256, 0, stream>>>(cycp, csuminv, cyc, b);
    }

    flow_kernel        <<<NB*2*65536/256, 256, 0, stream>>>(coords, out);
    imgout_kernel      <<<NB*3*65536/256, 256, 0, stream>>>(attn, cyc, out);
    loss_partial_kernel<<<1024,           256, 0, stream>>>(xf, yf, means, rnorms, lossp);
    loss_final_kernel  <<<1,              256, 0, stream>>>(lossp, out);
}